// Round 7
// baseline (52480.658 us; speedup 1.0000x reference)
//
#include <hip/hip_runtime.h>
#include <math.h>

#define HDIM 256
#define BATCH 64
#define TLEN 512
#define IDIM 64

typedef __attribute__((ext_vector_type(8))) short s16x8;
typedef __attribute__((ext_vector_type(4))) float f32x4;
typedef __attribute__((ext_vector_type(4))) unsigned int u32x4;

// ---------------- ws layout (float offsets) ----------------
static const size_t OFF_XG    = 0;
static const size_t OFF_YA    = 33554432;
static const size_t OFF_YB    = OFF_YA + 8388608;
static const size_t OFF_WIHT  = OFF_YB + 8388608;
static const size_t OFF_WHI   = OFF_WIHT + 1048576;
static const size_t OFF_WLO   = OFF_WHI + 524288;
static const size_t OFF_BSUM  = OFF_WLO + 524288;
static const size_t OFF_STATE = OFF_BSUM + 4096;

__device__ __forceinline__ float sig_(float x) { return 1.f / (1.f + __expf(-x)); }
__device__ __forceinline__ float tanh_(float x) { float e = __expf(2.f * x); return 1.f - 2.f / (e + 1.f); }

// RNE fp32 -> bf16 hi + bf16 lo, packed (hi<<16)|lo.
__device__ __forceinline__ unsigned int packhl(float h) {
    unsigned int u = __float_as_uint(h);
    unsigned int hb = (u + 0x7fffu + ((u >> 16) & 1u)) >> 16;
    float r = h - __uint_as_float(hb << 16);
    unsigned int ur = __float_as_uint(r);
    unsigned int lb = (ur + 0x7fffu + ((ur >> 16) & 1u)) >> 16;
    return (hb << 16) | (lb & 0xffffu);
}

// -------- prep --------
__global__ void prep_wih(const float* __restrict__ w, float* __restrict__ wt, int K) {
    int idx = blockIdx.x * 256 + threadIdx.x;
    if (idx >= 1024 * K) return;
    int n = idx / K, k = idx - n * K;
    int j = n >> 2, g = n & 3;
    wt[idx] = w[(g * 256 + j) * K + k];
}

__global__ void prep_whh_split(const float* __restrict__ w,
                               unsigned short* __restrict__ hi, unsigned short* __restrict__ lo) {
    int idx = blockIdx.x * 256 + threadIdx.x;
    float v = w[idx];
    unsigned int u = __float_as_uint(v);
    unsigned int hb = (u + 0x7fffu + ((u >> 16) & 1u)) >> 16;
    float r = v - __uint_as_float(hb << 16);
    unsigned int ur = __float_as_uint(r);
    unsigned int lb = (ur + 0x7fffu + ((ur >> 16) & 1u)) >> 16;
    hi[idx] = (unsigned short)hb;
    lo[idx] = (unsigned short)lb;
}

__global__ void prep_bias(const float* __restrict__ bi, const float* __restrict__ bh,
                          float* __restrict__ bs) {
    int n = blockIdx.x * 256 + threadIdx.x;
    int j = n >> 2, g = n & 3;
    bs[n] = bi[g * 256 + j] + bh[g * 256 + j];
}

// -------- projection GEMM (proven) --------
__global__ __launch_bounds__(256) void proj_kernel(
    const float* __restrict__ A, int K, int doRelu,
    const float* __restrict__ Wt, const float* __restrict__ bsum,
    float* __restrict__ out)
{
    __shared__ float As[16][128];
    __shared__ float Bs[16][128];
    const int tid = threadIdx.x;
    const int m0 = blockIdx.x * 128;
    const int n0 = blockIdx.y * 128;
    const int tx = tid & 15, ty = tid >> 4;

    float acc[8][8];
#pragma unroll
    for (int i = 0; i < 8; ++i)
#pragma unroll
        for (int j = 0; j < 8; ++j) acc[i][j] = 0.f;

    for (int kt = 0; kt < K; kt += 16) {
#pragma unroll
        for (int l = 0; l < 2; ++l) {
            int f = tid * 2 + l;
            int r = f >> 2;
            int c = (f & 3) << 2;
            float4 v = *(const float4*)&A[(size_t)(m0 + r) * K + kt + c];
            if (doRelu) {
                v.x = fmaxf(v.x, 0.f); v.y = fmaxf(v.y, 0.f);
                v.z = fmaxf(v.z, 0.f); v.w = fmaxf(v.w, 0.f);
            }
            As[c + 0][r] = v.x; As[c + 1][r] = v.y; As[c + 2][r] = v.z; As[c + 3][r] = v.w;
            float4 w = *(const float4*)&Wt[(size_t)(n0 + r) * K + kt + c];
            Bs[c + 0][r] = w.x; Bs[c + 1][r] = w.y; Bs[c + 2][r] = w.z; Bs[c + 3][r] = w.w;
        }
        __syncthreads();
#pragma unroll
        for (int kk = 0; kk < 16; ++kk) {
            float a[8], bb[8];
            *(float4*)&a[0]  = *(const float4*)&As[kk][ty * 8];
            *(float4*)&a[4]  = *(const float4*)&As[kk][ty * 8 + 4];
            *(float4*)&bb[0] = *(const float4*)&Bs[kk][tx * 8];
            *(float4*)&bb[4] = *(const float4*)&Bs[kk][tx * 8 + 4];
#pragma unroll
            for (int i = 0; i < 8; ++i)
#pragma unroll
                for (int j = 0; j < 8; ++j) acc[i][j] = fmaf(a[i], bb[j], acc[i][j]);
        }
        __syncthreads();
    }

    float bsv[8];
#pragma unroll
    for (int j = 0; j < 8; ++j) bsv[j] = bsum[n0 + tx * 8 + j];
#pragma unroll
    for (int i = 0; i < 8; ++i) {
        size_t row = (size_t)(m0 + ty * 8 + i);
        float4 o1 = { acc[i][0] + bsv[0], acc[i][1] + bsv[1], acc[i][2] + bsv[2], acc[i][3] + bsv[3] };
        float4 o2 = { acc[i][4] + bsv[4], acc[i][5] + bsv[5], acc[i][6] + bsv[6], acc[i][7] + bsv[7] };
        *(float4*)&out[row * 1024 + n0 + tx * 8]     = o1;
        *(float4*)&out[row * 1024 + n0 + tx * 8 + 4] = o2;
    }
}

// -------- recurrence v5: single-WG-per-group, LDS h exchange, no global sync --------
// 4 WGs x 1024 thr (16 waves). WG = 16 batches (bbase = bid*16). Wave w owns
// j-slice [w*16, w*16+16) for ALL 4 gates; weights 64 x s16x8 = 256 VGPRs,
// asm-pinned so the allocator cannot re-stream them from L2 (round-5 VGPR=184
// proved it does otherwise). h exchanged via LDS, packed (bf16hi|bf16lo) u32,
// double-buffered parity, ONE __syncthreads per step. Lane l (l15=lane&15,
// l4=lane>>4): MFMA A row=b=l15, k=l4*8+e; C/D col=j=l15, row=b=l4*4+r.
// LDS [b][k] row stride 260 u32: b128 reads conflict-free, writes 2-way (free).
__global__ __launch_bounds__(1024, 1) void rec_lds(
    const float* __restrict__ xg4,
    const unsigned short* __restrict__ whi, const unsigned short* __restrict__ wlo,
    float* __restrict__ y,
    const float* __restrict__ h_init, const float* __restrict__ c_init,
    float* __restrict__ h_save, float* __restrict__ c_save)
{
    __shared__ unsigned int hxl[2][16][260];
    const int tid  = threadIdx.x;
    const int lane = tid & 63;
    const int w    = tid >> 6;            // 0..15 j-slice
    const int bbase = blockIdx.x * 16;
    const int jw   = w * 16;
    const int l15  = lane & 15, l4 = lane >> 4;

    // persistent weights: [gate][ktile] = 256 VGPRs, pinned
    s16x8 bhi[4][8], blo[4][8];
#pragma unroll
    for (int g = 0; g < 4; ++g) {
        size_t rb = (size_t)(g * 256 + jw + l15) * 256 + l4 * 8;
#pragma unroll
        for (int kt = 0; kt < 8; ++kt) {
            bhi[g][kt] = *(const s16x8*)(whi + rb + kt * 32);
            blo[g][kt] = *(const s16x8*)(wlo + rb + kt * 32);
        }
    }
#pragma unroll
    for (int g = 0; g < 4; ++g)
#pragma unroll
        for (int kt = 0; kt < 8; ++kt) {
            asm volatile("" : "+v"(bhi[g][kt]));
            asm volatile("" : "+v"(blo[g][kt]));
        }

    // lane owns (b_local = l4*4+r, j = jw+l15), r = 0..3
    float h[4], c[4];
#pragma unroll
    for (int r = 0; r < 4; ++r) { h[r] = 0.f; c[r] = 0.f; }
    if (h_init != nullptr) {
#pragma unroll
        for (int r = 0; r < 4; ++r) {
            h[r] = h_init[(bbase + l4 * 4 + r) * 256 + jw + l15];
            c[r] = c_init[(bbase + l4 * 4 + r) * 256 + jw + l15];
        }
    }
    // publish h_0 into parity 0: hxl[0][b][k=j]
#pragma unroll
    for (int r = 0; r < 4; ++r)
        hxl[0][l4 * 4 + r][jw + l15] = packhl(h[r]);
    __syncthreads();

    for (int t = 0; t < TLEN; ++t) {
        // own x-gates (L3-resident), issued at loop top, consumed after MFMA
        float4 xv[4];
#pragma unroll
        for (int r = 0; r < 4; ++r)
            xv[r] = *(const float4*)&xg4[((size_t)(bbase + l4 * 4 + r) * TLEN + t) * 1024 + (jw + l15) * 4];

        const unsigned int* hrow = &hxl[t & 1][l15][0];   // A row = b = l15

        f32x4 aH[4], aC[4];
#pragma unroll
        for (int g = 0; g < 4; ++g) { aH[g] = (f32x4){0,0,0,0}; aC[g] = (f32x4){0,0,0,0}; }

#pragma unroll
        for (int kt = 0; kt < 8; ++kt) {
            u32x4 qa = *(const u32x4*)(hrow + kt * 32 + l4 * 8);
            u32x4 qb = *(const u32x4*)(hrow + kt * 32 + l4 * 8 + 4);
            union { unsigned int u[4]; s16x8 v; } ah, al;
            ah.u[0] = (qa[0] >> 16) | (qa[1] & 0xffff0000u);
            ah.u[1] = (qa[2] >> 16) | (qa[3] & 0xffff0000u);
            ah.u[2] = (qb[0] >> 16) | (qb[1] & 0xffff0000u);
            ah.u[3] = (qb[2] >> 16) | (qb[3] & 0xffff0000u);
            al.u[0] = (qa[0] & 0xffffu) | (qa[1] << 16);
            al.u[1] = (qa[2] & 0xffffu) | (qa[3] << 16);
            al.u[2] = (qb[0] & 0xffffu) | (qb[1] << 16);
            al.u[3] = (qb[2] & 0xffffu) | (qb[3] << 16);
#pragma unroll
            for (int g = 0; g < 4; ++g) {
                aH[g] = __builtin_amdgcn_mfma_f32_16x16x32_bf16(ah.v, bhi[g][kt], aH[g], 0, 0, 0);
                aC[g] = __builtin_amdgcn_mfma_f32_16x16x32_bf16(al.v, bhi[g][kt], aC[g], 0, 0, 0);
                aC[g] = __builtin_amdgcn_mfma_f32_16x16x32_bf16(ah.v, blo[g][kt], aC[g], 0, 0, 0);
            }
        }

        // in-lane nonlinearity + LDS publish of h_{t+1} + y store
        const int nxt = (t + 1) & 1;
#pragma unroll
        for (int r = 0; r < 4; ++r) {
            float si = aH[0][r] + aC[0][r] + xv[r].x;
            float sf = aH[1][r] + aC[1][r] + xv[r].y;
            float sg = aH[2][r] + aC[2][r] + xv[r].z;
            float so = aH[3][r] + aC[3][r] + xv[r].w;
            float ig = sig_(si);
            float fg = sig_(sf);
            float gg = tanh_(sg);
            float og = sig_(so);
            c[r] = fmaf(fg, c[r], ig * gg);
            h[r] = og * tanh_(c[r]);
            hxl[nxt][l4 * 4 + r][jw + l15] = packhl(h[r]);
            y[((size_t)(bbase + l4 * 4 + r) * TLEN + t) * 256 + jw + l15] = h[r];
        }
        __syncthreads();   // parity buffer ready; prev reads all complete
    }

    if (h_save != nullptr) {
#pragma unroll
        for (int r = 0; r < 4; ++r) {
            h_save[(bbase + l4 * 4 + r) * 256 + jw + l15] = h[r];
            c_save[(bbase + l4 * 4 + r) * 256 + jw + l15] = c[r];
        }
    }
}

// -------- head --------
__global__ __launch_bounds__(256) void head_kernel(const float* __restrict__ y3,
    const float* __restrict__ lin_w, const float* __restrict__ lin_b, float* __restrict__ out)
{
    int b = blockIdx.x;
    int tid = threadIdx.x;
    float v = y3[((size_t)b * TLEN + (TLEN - 1)) * HDIM + tid] * lin_w[tid];
#pragma unroll
    for (int o = 32; o > 0; o >>= 1) v += __shfl_down(v, o);
    __shared__ float red[4];
    int wid = tid >> 6, lane = tid & 63;
    if (lane == 0) red[wid] = v;
    __syncthreads();
    if (tid == 0) out[b] = red[0] + red[1] + red[2] + red[3] + lin_b[0];
}

extern "C" void kernel_launch(void* const* d_in, const int* in_sizes, int n_in,
                              void* d_out, int out_size, void* d_ws, size_t ws_size,
                              hipStream_t stream) {
    const float* x = (const float*)d_in[0];
    const float* wih[4] = { (const float*)d_in[1], (const float*)d_in[5], (const float*)d_in[9],  (const float*)d_in[13] };
    const float* whh[4] = { (const float*)d_in[2], (const float*)d_in[6], (const float*)d_in[10], (const float*)d_in[14] };
    const float* bih[4] = { (const float*)d_in[3], (const float*)d_in[7], (const float*)d_in[11], (const float*)d_in[15] };
    const float* bhh[4] = { (const float*)d_in[4], (const float*)d_in[8], (const float*)d_in[12], (const float*)d_in[16] };
    const float* lin_w = (const float*)d_in[17];
    const float* lin_b = (const float*)d_in[18];
    float* ws = (float*)d_ws;

    float* xg4  = ws + OFF_XG;
    float* yA   = ws + OFF_YA;
    float* yB   = ws + OFF_YB;
    float* wihT = ws + OFF_WIHT;
    unsigned short* whiB = (unsigned short*)(ws + OFF_WHI);
    unsigned short* wloB = (unsigned short*)(ws + OFF_WLO);
    float* bsum = ws + OFF_BSUM;
    float* h0T  = ws + OFF_STATE;
    float* c0T  = h0T + BATCH * HDIM;
    float* h1T  = c0T + BATCH * HDIM;
    float* c1T  = h1T + BATCH * HDIM;

    for (int l = 0; l < 4; ++l) {
        int K = (l == 0) ? IDIM : HDIM;
        prep_wih<<<dim3((1024 * K + 255) / 256), 256, 0, stream>>>(wih[l], wihT + (size_t)l * 262144, K);
        prep_whh_split<<<dim3(1024), 256, 0, stream>>>(whh[l], whiB + (size_t)l * 262144, wloB + (size_t)l * 262144);
        prep_bias<<<dim3(4), 256, 0, stream>>>(bih[l], bhh[l], bsum + l * 1024);
    }

    dim3 pgrid(256, 8);
    dim3 rgrid(4);

    proj_kernel<<<pgrid, 256, 0, stream>>>(x, IDIM, 1, wihT + 0 * 262144, bsum + 0 * 1024, xg4);
    rec_lds<<<rgrid, 1024, 0, stream>>>(xg4, whiB + 0 * 262144, wloB + 0 * 262144, yA,
                                        nullptr, nullptr, h0T, c0T);

    proj_kernel<<<pgrid, 256, 0, stream>>>(yA, HDIM, 0, wihT + 1 * 262144, bsum + 1 * 1024, xg4);
    rec_lds<<<rgrid, 1024, 0, stream>>>(xg4, whiB + 1 * 262144, wloB + 1 * 262144, yB,
                                        nullptr, nullptr, h1T, c1T);

    proj_kernel<<<pgrid, 256, 0, stream>>>(yB, HDIM, 1, wihT + 2 * 262144, bsum + 2 * 1024, xg4);
    rec_lds<<<rgrid, 1024, 0, stream>>>(xg4, whiB + 2 * 262144, wloB + 2 * 262144, yA,
                                        h0T, c0T, nullptr, nullptr);

    proj_kernel<<<pgrid, 256, 0, stream>>>(yA, HDIM, 0, wihT + 3 * 262144, bsum + 3 * 1024, xg4);
    rec_lds<<<rgrid, 1024, 0, stream>>>(xg4, whiB + 3 * 262144, wloB + 3 * 262144, yB,
                                        h1T, c1T, nullptr, nullptr);

    head_kernel<<<dim3(BATCH), 256, 0, stream>>>(yB, lin_w, lin_b, (float*)d_out);
}

// Round 8
// 11774.541 us; speedup vs baseline: 4.4571x; 4.4571x over previous
//
#include <hip/hip_runtime.h>
#include <math.h>

#define HDIM 256
#define BATCH 64
#define TLEN 512
#define IDIM 64

typedef __attribute__((ext_vector_type(8))) short s16x8;
typedef __attribute__((ext_vector_type(4))) float f32x4;

// ---------------- ws layout (float offsets) ----------------
static const size_t OFF_XG    = 0;
static const size_t OFF_YA    = 33554432;
static const size_t OFF_YB    = OFF_YA + 8388608;
static const size_t OFF_WIHT  = OFF_YB + 8388608;
static const size_t OFF_WHI   = OFF_WIHT + 1048576;
static const size_t OFF_WLO   = OFF_WHI + 524288;
static const size_t OFF_BSUM  = OFF_WLO + 524288;
static const size_t OFF_STATE = OFF_BSUM + 4096;
static const size_t OFF_HXP   = OFF_STATE + 65536;   // [2][64][256] u32
static const size_t OFF_CTR   = OFF_HXP + 32768;     // flags: 4 layers x 16 ints

__device__ __forceinline__ float sig_(float x) { return 1.f / (1.f + __expf(-x)); }
__device__ __forceinline__ float tanh_(float x) { float e = __expf(2.f * x); return 1.f - 2.f / (e + 1.f); }

__device__ __forceinline__ unsigned int packhl(float h) {
    unsigned int u = __float_as_uint(h);
    unsigned int hb = (u + 0x7fffu + ((u >> 16) & 1u)) >> 16;
    float r = h - __uint_as_float(hb << 16);
    unsigned int ur = __float_as_uint(r);
    unsigned int lb = (ur + 0x7fffu + ((ur >> 16) & 1u)) >> 16;
    return (hb << 16) | (lb & 0xffffu);
}

__device__ __forceinline__ void st_llc(unsigned int* p, unsigned int v) {
    __hip_atomic_store(p, v, __ATOMIC_RELAXED, __HIP_MEMORY_SCOPE_AGENT);
}
__device__ __forceinline__ unsigned long long ld_llc8(const unsigned int* p) {
    return __hip_atomic_load((const unsigned long long*)p, __ATOMIC_RELAXED, __HIP_MEMORY_SCOPE_AGENT);
}

// -------- prep --------
__global__ void prep_wih(const float* __restrict__ w, float* __restrict__ wt, int K) {
    int idx = blockIdx.x * 256 + threadIdx.x;
    if (idx >= 1024 * K) return;
    int n = idx / K, k = idx - n * K;
    int j = n >> 2, g = n & 3;
    wt[idx] = w[(g * 256 + j) * K + k];
}

__global__ void prep_whh_split(const float* __restrict__ w,
                               unsigned short* __restrict__ hi, unsigned short* __restrict__ lo) {
    int idx = blockIdx.x * 256 + threadIdx.x;
    float v = w[idx];
    unsigned int u = __float_as_uint(v);
    unsigned int hb = (u + 0x7fffu + ((u >> 16) & 1u)) >> 16;
    float r = v - __uint_as_float(hb << 16);
    unsigned int ur = __float_as_uint(r);
    unsigned int lb = (ur + 0x7fffu + ((ur >> 16) & 1u)) >> 16;
    hi[idx] = (unsigned short)hb;
    lo[idx] = (unsigned short)lb;
}

__global__ void prep_bias(const float* __restrict__ bi, const float* __restrict__ bh,
                          float* __restrict__ bs) {
    int n = blockIdx.x * 256 + threadIdx.x;
    int j = n >> 2, g = n & 3;
    bs[n] = bi[g * 256 + j] + bh[g * 256 + j];
}

// -------- projection GEMM (proven) --------
__global__ __launch_bounds__(256) void proj_kernel(
    const float* __restrict__ A, int K, int doRelu,
    const float* __restrict__ Wt, const float* __restrict__ bsum,
    float* __restrict__ out)
{
    __shared__ float As[16][128];
    __shared__ float Bs[16][128];
    const int tid = threadIdx.x;
    const int m0 = blockIdx.x * 128;
    const int n0 = blockIdx.y * 128;
    const int tx = tid & 15, ty = tid >> 4;

    float acc[8][8];
#pragma unroll
    for (int i = 0; i < 8; ++i)
#pragma unroll
        for (int j = 0; j < 8; ++j) acc[i][j] = 0.f;

    for (int kt = 0; kt < K; kt += 16) {
#pragma unroll
        for (int l = 0; l < 2; ++l) {
            int f = tid * 2 + l;
            int r = f >> 2;
            int c = (f & 3) << 2;
            float4 v = *(const float4*)&A[(size_t)(m0 + r) * K + kt + c];
            if (doRelu) {
                v.x = fmaxf(v.x, 0.f); v.y = fmaxf(v.y, 0.f);
                v.z = fmaxf(v.z, 0.f); v.w = fmaxf(v.w, 0.f);
            }
            As[c + 0][r] = v.x; As[c + 1][r] = v.y; As[c + 2][r] = v.z; As[c + 3][r] = v.w;
            float4 w = *(const float4*)&Wt[(size_t)(n0 + r) * K + kt + c];
            Bs[c + 0][r] = w.x; Bs[c + 1][r] = w.y; Bs[c + 2][r] = w.z; Bs[c + 3][r] = w.w;
        }
        __syncthreads();
#pragma unroll
        for (int kk = 0; kk < 16; ++kk) {
            float a[8], bb[8];
            *(float4*)&a[0]  = *(const float4*)&As[kk][ty * 8];
            *(float4*)&a[4]  = *(const float4*)&As[kk][ty * 8 + 4];
            *(float4*)&bb[0] = *(const float4*)&Bs[kk][tx * 8];
            *(float4*)&bb[4] = *(const float4*)&Bs[kk][tx * 8 + 4];
#pragma unroll
            for (int i = 0; i < 8; ++i)
#pragma unroll
                for (int j = 0; j < 8; ++j) acc[i][j] = fmaf(a[i], bb[j], acc[i][j]);
        }
        __syncthreads();
    }

    float bsv[8];
#pragma unroll
    for (int j = 0; j < 8; ++j) bsv[j] = bsum[n0 + tx * 8 + j];
#pragma unroll
    for (int i = 0; i < 8; ++i) {
        size_t row = (size_t)(m0 + ty * 8 + i);
        float4 o1 = { acc[i][0] + bsv[0], acc[i][1] + bsv[1], acc[i][2] + bsv[2], acc[i][3] + bsv[3] };
        float4 o2 = { acc[i][4] + bsv[4], acc[i][5] + bsv[5], acc[i][6] + bsv[6], acc[i][7] + bsv[7] };
        *(float4*)&out[row * 1024 + n0 + tx * 8]     = o1;
        *(float4*)&out[row * 1024 + n0 + tx * 8 + 4] = o2;
    }
}

// -------- cooperative recurrence v6: k-split waves, 128 weight VGPRs/thread --------
// 16 WGs x 512 thr. group gid=bid&3 (16 batches), j-slice wgj=bid>>2 (64 j).
// 8 waves = (js=w&3: 16 j) x (kh=w>>2: 128 k). Weights bhi/blo[4 gates][4 kt]
// = 128 VGPRs, pinned; demand ~230 < 256 cap (512-thr block, 2 waves/SIMD).
// k-halves combine gate partials via LDS (1 barrier); publish split: kh0 owns
// batch rows 0,1; kh1 rows 2,3. Handshake: monotone per-WG flag (plain sc1
// store, no RMW); consumer tid0 polls the group's 4 flags (2x8B LLC loads).
__global__ __launch_bounds__(512, 2) void rec_coop2(
    const float* __restrict__ xg4,
    const unsigned short* __restrict__ whi, const unsigned short* __restrict__ wlo,
    float* __restrict__ y,
    const float* __restrict__ h_init, const float* __restrict__ c_init,
    float* __restrict__ h_save, float* __restrict__ c_save,
    unsigned int* __restrict__ hxp, int* __restrict__ ctr)
{
    __shared__ float4 part[2][4][4][64];   // [kh][js][gate][l4*16+l15], 32 KB
    const int tid  = threadIdx.x;
    const int lane = tid & 63;
    const int w    = tid >> 6;
    const int js   = w & 3;
    const int kh   = w >> 2;
    const int gid  = blockIdx.x & 3;
    const int wgj  = blockIdx.x >> 2;
    const int bbase = gid * 16;
    const int jw   = wgj * 64 + js * 16;
    const int l15  = lane & 15, l4 = lane >> 4;
    const int kbase = kh * 128;
    unsigned int* flags = (unsigned int*)(ctr) + gid * 4;   // this group's 4 flags

    // persistent weights: [gate][kt] = 128 VGPRs, pinned
    s16x8 bhi[4][4], blo[4][4];
#pragma unroll
    for (int g = 0; g < 4; ++g) {
        size_t rb = (size_t)(g * 256 + jw + l15) * 256 + kbase + l4 * 8;
#pragma unroll
        for (int kt = 0; kt < 4; ++kt) {
            bhi[g][kt] = *(const s16x8*)(whi + rb + kt * 32);
            blo[g][kt] = *(const s16x8*)(wlo + rb + kt * 32);
        }
    }
#pragma unroll
    for (int g = 0; g < 4; ++g)
#pragma unroll
        for (int kt = 0; kt < 4; ++kt) {
            asm volatile("" : "+v"(bhi[g][kt]));
            asm volatile("" : "+v"(blo[g][kt]));
        }

    // this thread finalizes batch rows r0=kh*2, r0+1 for j = jw+l15
    const int b0 = bbase + l4 * 4 + kh * 2;
    const int b1 = b0 + 1;
    float h0v = 0.f, h1v = 0.f, c0v = 0.f, c1v = 0.f;
    if (h_init != nullptr) {
        h0v = h_init[b0 * 256 + jw + l15];
        h1v = h_init[b1 * 256 + jw + l15];
        c0v = c_init[b0 * 256 + jw + l15];
        c1v = c_init[b1 * 256 + jw + l15];
    }
    // publish h_0 into parity 0 (each thread: 2 rows -> all 16 rows covered)
    st_llc(&hxp[(size_t)b0 * 256 + jw + l15], packhl(h0v));
    st_llc(&hxp[(size_t)b1 * 256 + jw + l15], packhl(h1v));
    __syncthreads();   // drain all publishes
    if (tid == 0) st_llc(&flags[wgj], 1u);

    for (int t = 0; t < TLEN; ++t) {
        // own x-gates (independent), issue before the poll
        float4 xv0 = *(const float4*)&xg4[((size_t)b0 * TLEN + t) * 1024 + (jw + l15) * 4];
        float4 xv1 = *(const float4*)&xg4[((size_t)b1 * TLEN + t) * 1024 + (jw + l15) * 4];

        if (tid == 0) {
            int target = t + 1;
            for (;;) {
                unsigned long long qa = ld_llc8(&flags[0]);
                unsigned long long qb = ld_llc8(&flags[2]);
                if ((int)qa >= target && (int)(qa >> 32) >= target &&
                    (int)qb >= target && (int)(qb >> 32) >= target) break;
                __builtin_amdgcn_s_sleep(1);
            }
        }
        __syncthreads();
        asm volatile("" ::: "memory");

        // h for all 16 batches, own k-half: 4 kt x 32B
        const unsigned int* hp = hxp + (size_t)(t & 1) * 16384
                                 + (size_t)(bbase + l15) * 256 + kbase + l4 * 8;
        unsigned long long q[16];
#pragma unroll
        for (int kt = 0; kt < 4; ++kt) {
            q[kt * 4 + 0] = ld_llc8(hp + kt * 32 + 0);
            q[kt * 4 + 1] = ld_llc8(hp + kt * 32 + 2);
            q[kt * 4 + 2] = ld_llc8(hp + kt * 32 + 4);
            q[kt * 4 + 3] = ld_llc8(hp + kt * 32 + 6);
        }

        f32x4 aH[4], aC[4];
#pragma unroll
        for (int g = 0; g < 4; ++g) { aH[g] = (f32x4){0,0,0,0}; aC[g] = (f32x4){0,0,0,0}; }

#pragma unroll
        for (int kt = 0; kt < 4; ++kt) {
            unsigned int w0 = (unsigned int)q[kt*4+0], w1 = (unsigned int)(q[kt*4+0] >> 32);
            unsigned int w2 = (unsigned int)q[kt*4+1], w3 = (unsigned int)(q[kt*4+1] >> 32);
            unsigned int w4 = (unsigned int)q[kt*4+2], w5 = (unsigned int)(q[kt*4+2] >> 32);
            unsigned int w6 = (unsigned int)q[kt*4+3], w7 = (unsigned int)(q[kt*4+3] >> 32);
            union { unsigned int u[4]; s16x8 v; } ah, al;
            ah.u[0] = (w0 >> 16) | (w1 & 0xffff0000u);
            ah.u[1] = (w2 >> 16) | (w3 & 0xffff0000u);
            ah.u[2] = (w4 >> 16) | (w5 & 0xffff0000u);
            ah.u[3] = (w6 >> 16) | (w7 & 0xffff0000u);
            al.u[0] = (w0 & 0xffffu) | (w1 << 16);
            al.u[1] = (w2 & 0xffffu) | (w3 << 16);
            al.u[2] = (w4 & 0xffffu) | (w5 << 16);
            al.u[3] = (w6 & 0xffffu) | (w7 << 16);
#pragma unroll
            for (int g = 0; g < 4; ++g) {
                aH[g] = __builtin_amdgcn_mfma_f32_16x16x32_bf16(ah.v, bhi[g][kt], aH[g], 0, 0, 0);
                aC[g] = __builtin_amdgcn_mfma_f32_16x16x32_bf16(al.v, bhi[g][kt], aC[g], 0, 0, 0);
                aC[g] = __builtin_amdgcn_mfma_f32_16x16x32_bf16(ah.v, blo[g][kt], aC[g], 0, 0, 0);
            }
        }

        // cross-k-half combine via LDS
        const int widx = l4 * 16 + l15;
        f32x4 s0 = aH[0] + aC[0], s1 = aH[1] + aC[1], s2 = aH[2] + aC[2], s3 = aH[3] + aC[3];
        part[kh][js][0][widx] = (float4){s0[0], s0[1], s0[2], s0[3]};
        part[kh][js][1][widx] = (float4){s1[0], s1[1], s1[2], s1[3]};
        part[kh][js][2][widx] = (float4){s2[0], s2[1], s2[2], s2[3]};
        part[kh][js][3][widx] = (float4){s3[0], s3[1], s3[2], s3[3]};
        __syncthreads();
        float4 o0 = part[kh ^ 1][js][0][widx];
        float4 o1 = part[kh ^ 1][js][1][widx];
        float4 o2 = part[kh ^ 1][js][2][widx];
        float4 o3 = part[kh ^ 1][js][3][widx];

        // finalize own 2 rows (wave-uniform branch on kh -> static vector idx)
        float si0, sf0, sg0, so0, si1, sf1, sg1, so1;
        if (kh == 0) {
            si0 = s0[0] + o0.x; sf0 = s1[0] + o1.x; sg0 = s2[0] + o2.x; so0 = s3[0] + o3.x;
            si1 = s0[1] + o0.y; sf1 = s1[1] + o1.y; sg1 = s2[1] + o2.y; so1 = s3[1] + o3.y;
        } else {
            si0 = s0[2] + o0.z; sf0 = s1[2] + o1.z; sg0 = s2[2] + o2.z; so0 = s3[2] + o3.z;
            si1 = s0[3] + o0.w; sf1 = s1[3] + o1.w; sg1 = s2[3] + o2.w; so1 = s3[3] + o3.w;
        }

        size_t hb2 = (size_t)((t + 1) & 1) * 16384;
        {
            float ig = sig_(si0 + xv0.x);
            float fg = sig_(sf0 + xv0.y);
            float gg = tanh_(sg0 + xv0.z);
            float og = sig_(so0 + xv0.w);
            c0v = fmaf(fg, c0v, ig * gg);
            h0v = og * tanh_(c0v);
            st_llc(&hxp[hb2 + (size_t)b0 * 256 + jw + l15], packhl(h0v));
            y[((size_t)b0 * TLEN + t) * 256 + jw + l15] = h0v;
        }
        {
            float ig = sig_(si1 + xv1.x);
            float fg = sig_(sf1 + xv1.y);
            float gg = tanh_(sg1 + xv1.z);
            float og = sig_(so1 + xv1.w);
            c1v = fmaf(fg, c1v, ig * gg);
            h1v = og * tanh_(c1v);
            st_llc(&hxp[hb2 + (size_t)b1 * 256 + jw + l15], packhl(h1v));
            y[((size_t)b1 * TLEN + t) * 256 + jw + l15] = h1v;
        }

        __syncthreads();   // vmcnt(0)/lds drain: h publishes ack'd at LLC
        asm volatile("" ::: "memory");
        if (tid == 0) st_llc(&flags[wgj], (unsigned int)(t + 2));
    }

    if (h_save != nullptr) {
        h_save[b0 * 256 + jw + l15] = h0v;
        h_save[b1 * 256 + jw + l15] = h1v;
        c_save[b0 * 256 + jw + l15] = c0v;
        c_save[b1 * 256 + jw + l15] = c1v;
    }
}

// -------- head --------
__global__ __launch_bounds__(256) void head_kernel(const float* __restrict__ y3,
    const float* __restrict__ lin_w, const float* __restrict__ lin_b, float* __restrict__ out)
{
    int b = blockIdx.x;
    int tid = threadIdx.x;
    float v = y3[((size_t)b * TLEN + (TLEN - 1)) * HDIM + tid] * lin_w[tid];
#pragma unroll
    for (int o = 32; o > 0; o >>= 1) v += __shfl_down(v, o);
    __shared__ float red[4];
    int wid = tid >> 6, lane = tid & 63;
    if (lane == 0) red[wid] = v;
    __syncthreads();
    if (tid == 0) out[b] = red[0] + red[1] + red[2] + red[3] + lin_b[0];
}

extern "C" void kernel_launch(void* const* d_in, const int* in_sizes, int n_in,
                              void* d_out, int out_size, void* d_ws, size_t ws_size,
                              hipStream_t stream) {
    const float* x = (const float*)d_in[0];
    const float* wih[4] = { (const float*)d_in[1], (const float*)d_in[5], (const float*)d_in[9],  (const float*)d_in[13] };
    const float* whh[4] = { (const float*)d_in[2], (const float*)d_in[6], (const float*)d_in[10], (const float*)d_in[14] };
    const float* bih[4] = { (const float*)d_in[3], (const float*)d_in[7], (const float*)d_in[11], (const float*)d_in[15] };
    const float* bhh[4] = { (const float*)d_in[4], (const float*)d_in[8], (const float*)d_in[12], (const float*)d_in[16] };
    const float* lin_w = (const float*)d_in[17];
    const float* lin_b = (const float*)d_in[18];
    float* ws = (float*)d_ws;

    float* xg4  = ws + OFF_XG;
    float* yA   = ws + OFF_YA;
    float* yB   = ws + OFF_YB;
    float* wihT = ws + OFF_WIHT;
    unsigned short* whiB = (unsigned short*)(ws + OFF_WHI);
    unsigned short* wloB = (unsigned short*)(ws + OFF_WLO);
    float* bsum = ws + OFF_BSUM;
    float* h0T  = ws + OFF_STATE;
    float* c0T  = h0T + BATCH * HDIM;
    float* h1T  = c0T + BATCH * HDIM;
    float* c1T  = h1T + BATCH * HDIM;
    unsigned int* hxp = (unsigned int*)(ws + OFF_HXP);
    int* ctr = (int*)(ws + OFF_CTR);

    // flags: 4 layers x 4 groups x 4 WGs ints
    hipMemsetAsync(ctr, 0, 4 * 16 * sizeof(int), stream);

    for (int l = 0; l < 4; ++l) {
        int K = (l == 0) ? IDIM : HDIM;
        prep_wih<<<dim3((1024 * K + 255) / 256), 256, 0, stream>>>(wih[l], wihT + (size_t)l * 262144, K);
        prep_whh_split<<<dim3(1024), 256, 0, stream>>>(whh[l], whiB + (size_t)l * 262144, wloB + (size_t)l * 262144);
        prep_bias<<<dim3(4), 256, 0, stream>>>(bih[l], bhh[l], bsum + l * 1024);
    }

    dim3 pgrid(256, 8);
    dim3 rgrid(16);

    proj_kernel<<<pgrid, 256, 0, stream>>>(x, IDIM, 1, wihT + 0 * 262144, bsum + 0 * 1024, xg4);
    rec_coop2<<<rgrid, 512, 0, stream>>>(xg4, whiB + 0 * 262144, wloB + 0 * 262144, yA,
                                         nullptr, nullptr, h0T, c0T, hxp, ctr + 0 * 16);

    proj_kernel<<<pgrid, 256, 0, stream>>>(yA, HDIM, 0, wihT + 1 * 262144, bsum + 1 * 1024, xg4);
    rec_coop2<<<rgrid, 512, 0, stream>>>(xg4, whiB + 1 * 262144, wloB + 1 * 262144, yB,
                                         nullptr, nullptr, h1T, c1T, hxp, ctr + 1 * 16);

    proj_kernel<<<pgrid, 256, 0, stream>>>(yB, HDIM, 1, wihT + 2 * 262144, bsum + 2 * 1024, xg4);
    rec_coop2<<<rgrid, 512, 0, stream>>>(xg4, whiB + 2 * 262144, wloB + 2 * 262144, yA,
                                         h0T, c0T, nullptr, nullptr, hxp, ctr + 2 * 16);

    proj_kernel<<<pgrid, 256, 0, stream>>>(yA, HDIM, 0, wihT + 3 * 262144, bsum + 3 * 1024, xg4);
    rec_coop2<<<rgrid, 512, 0, stream>>>(xg4, whiB + 3 * 262144, wloB + 3 * 262144, yB,
                                         h1T, c1T, nullptr, nullptr, hxp, ctr + 3 * 16);

    head_kernel<<<dim3(BATCH), 256, 0, stream>>>(yB, lin_w, lin_b, (float*)d_out);
}

// Round 10
// 6209.337 us; speedup vs baseline: 8.4519x; 1.8963x over previous
//
#include <hip/hip_runtime.h>
#include <math.h>

#define HDIM 256
#define BATCH 64
#define TLEN 512
#define IDIM 64

typedef __attribute__((ext_vector_type(8))) short s16x8;
typedef __attribute__((ext_vector_type(4))) float f32x4;
typedef unsigned long long u64;

// ---------------- ws layout (float offsets) ----------------
static const size_t OFF_XG    = 0;                   // phase A: xg4 [64][512][1024] f32; phase B: y2pk (u32) aliased
static const size_t OFF_Y0PK  = 33554432;            // [64][512][256] u32
static const size_t OFF_Y1PK  = OFF_Y0PK + 8388608;  // 41943040 (relu'd y1 stream)
static const size_t OFF_WIHT0 = OFF_Y1PK + 8388608;  // 50331648, wihT layer0a fp32 [1024][64]
static const size_t OFF_WHHHI = OFF_WIHT0 + 65536;   // 50397184, 4 x 131072 f32 (262144 ushort each)
static const size_t OFF_WHHLO = OFF_WHHHI + 524288;  // 50921472
static const size_t OFF_WIHHI = OFF_WHHLO + 524288;  // 51445760, 3 x 131072
static const size_t OFF_WIHLO = OFF_WIHHI + 393216;  // 51838976
static const size_t OFF_BSUM  = OFF_WIHLO + 393216;  // 52232192, 4 x 1024
static const size_t OFF_STATE = OFF_BSUM + 4096;     // 52236288, h0T,c0T,h1T,c1T,h3T (5 x 16384)
static const size_t OFF_HXP   = OFF_STATE + 81920;   // 52318208, 2 stages x [2][64][256] u32
static const size_t OFF_FLG   = OFF_HXP + 65536;     // 52383744, 128 ints (phase A: 64, phase B: 64)

__device__ __forceinline__ float sig_(float x) { return 1.f / (1.f + __expf(-x)); }
__device__ __forceinline__ float tanh_(float x) { float e = __expf(2.f * x); return 1.f - 2.f / (e + 1.f); }

__device__ __forceinline__ unsigned int packhl(float h) {
    unsigned int u = __float_as_uint(h);
    unsigned int hb = (u + 0x7fffu + ((u >> 16) & 1u)) >> 16;
    float r = h - __uint_as_float(hb << 16);
    unsigned int ur = __float_as_uint(r);
    unsigned int lb = (ur + 0x7fffu + ((ur >> 16) & 1u)) >> 16;
    return (hb << 16) | (lb & 0xffffu);
}

__device__ __forceinline__ void st_llc(unsigned int* p, unsigned int v) {
    __hip_atomic_store(p, v, __ATOMIC_RELAXED, __HIP_MEMORY_SCOPE_AGENT);
}
__device__ __forceinline__ u64 ld_llc8(const unsigned int* p) {
    return __hip_atomic_load((const u64*)p, __ATOMIC_RELAXED, __HIP_MEMORY_SCOPE_AGENT);
}

__device__ __forceinline__ void unpack_hl(u64 q0, u64 q1, u64 q2, u64 q3, s16x8& ah, s16x8& al) {
    unsigned int w0 = (unsigned int)q0, w1 = (unsigned int)(q0 >> 32);
    unsigned int w2 = (unsigned int)q1, w3 = (unsigned int)(q1 >> 32);
    unsigned int w4 = (unsigned int)q2, w5 = (unsigned int)(q2 >> 32);
    unsigned int w6 = (unsigned int)q3, w7 = (unsigned int)(q3 >> 32);
    union { unsigned int u[4]; s16x8 v; } H, L;
    H.u[0] = (w0 >> 16) | (w1 & 0xffff0000u);
    H.u[1] = (w2 >> 16) | (w3 & 0xffff0000u);
    H.u[2] = (w4 >> 16) | (w5 & 0xffff0000u);
    H.u[3] = (w6 >> 16) | (w7 & 0xffff0000u);
    L.u[0] = (w0 & 0xffffu) | (w1 << 16);
    L.u[1] = (w2 & 0xffffu) | (w3 << 16);
    L.u[2] = (w4 & 0xffffu) | (w5 << 16);
    L.u[3] = (w6 & 0xffffu) | (w7 << 16);
    ah = H.v; al = L.v;
}

// -------- prep --------
__global__ void prep_wih(const float* __restrict__ w, float* __restrict__ wt, int K) {
    int idx = blockIdx.x * 256 + threadIdx.x;
    if (idx >= 1024 * K) return;
    int n = idx / K, k = idx - n * K;
    int j = n >> 2, g = n & 3;
    wt[idx] = w[(g * 256 + j) * K + k];
}

// split any [1024][256] fp32 matrix (rows g*256+j) into bf16 hi/lo, layout preserved
__global__ void prep_split(const float* __restrict__ w,
                           unsigned short* __restrict__ hi, unsigned short* __restrict__ lo) {
    int idx = blockIdx.x * 256 + threadIdx.x;
    float v = w[idx];
    unsigned int u = __float_as_uint(v);
    unsigned int hb = (u + 0x7fffu + ((u >> 16) & 1u)) >> 16;
    float r = v - __uint_as_float(hb << 16);
    unsigned int ur = __float_as_uint(r);
    unsigned int lb = (ur + 0x7fffu + ((ur >> 16) & 1u)) >> 16;
    hi[idx] = (unsigned short)hb;
    lo[idx] = (unsigned short)lb;
}

__global__ void prep_bias(const float* __restrict__ bi, const float* __restrict__ bh,
                          float* __restrict__ bs) {
    int n = blockIdx.x * 256 + threadIdx.x;
    int j = n >> 2, g = n & 3;
    bs[n] = bi[g * 256 + j] + bh[g * 256 + j];
}

// -------- projection GEMM (proven; layer 0a only, K=64) --------
__global__ __launch_bounds__(256) void proj_kernel(
    const float* __restrict__ A, int K, int doRelu,
    const float* __restrict__ Wt, const float* __restrict__ bsum,
    float* __restrict__ out)
{
    __shared__ float As[16][128];
    __shared__ float Bs[16][128];
    const int tid = threadIdx.x;
    const int m0 = blockIdx.x * 128;
    const int n0 = blockIdx.y * 128;
    const int tx = tid & 15, ty = tid >> 4;

    float acc[8][8];
#pragma unroll
    for (int i = 0; i < 8; ++i)
#pragma unroll
        for (int j = 0; j < 8; ++j) acc[i][j] = 0.f;

    for (int kt = 0; kt < K; kt += 16) {
#pragma unroll
        for (int l = 0; l < 2; ++l) {
            int f = tid * 2 + l;
            int r = f >> 2;
            int c = (f & 3) << 2;
            float4 v = *(const float4*)&A[(size_t)(m0 + r) * K + kt + c];
            if (doRelu) {
                v.x = fmaxf(v.x, 0.f); v.y = fmaxf(v.y, 0.f);
                v.z = fmaxf(v.z, 0.f); v.w = fmaxf(v.w, 0.f);
            }
            As[c + 0][r] = v.x; As[c + 1][r] = v.y; As[c + 2][r] = v.z; As[c + 3][r] = v.w;
            float4 w = *(const float4*)&Wt[(size_t)(n0 + r) * K + kt + c];
            Bs[c + 0][r] = w.x; Bs[c + 1][r] = w.y; Bs[c + 2][r] = w.z; Bs[c + 3][r] = w.w;
        }
        __syncthreads();
#pragma unroll
        for (int kk = 0; kk < 16; ++kk) {
            float a[8], bb[8];
            *(float4*)&a[0]  = *(const float4*)&As[kk][ty * 8];
            *(float4*)&a[4]  = *(const float4*)&As[kk][ty * 8 + 4];
            *(float4*)&bb[0] = *(const float4*)&Bs[kk][tx * 8];
            *(float4*)&bb[4] = *(const float4*)&Bs[kk][tx * 8 + 4];
#pragma unroll
            for (int i = 0; i < 8; ++i)
#pragma unroll
                for (int j = 0; j < 8; ++j) acc[i][j] = fmaf(a[i], bb[j], acc[i][j]);
        }
        __syncthreads();
    }

    float bsv[8];
#pragma unroll
    for (int j = 0; j < 8; ++j) bsv[j] = bsum[n0 + tx * 8 + j];
#pragma unroll
    for (int i = 0; i < 8; ++i) {
        size_t row = (size_t)(m0 + ty * 8 + i);
        float4 o1 = { acc[i][0] + bsv[0], acc[i][1] + bsv[1], acc[i][2] + bsv[2], acc[i][3] + bsv[3] };
        float4 o2 = { acc[i][4] + bsv[4], acc[i][5] + bsv[5], acc[i][6] + bsv[6], acc[i][7] + bsv[7] };
        *(float4*)&out[row * 1024 + n0 + tx * 8]     = o1;
        *(float4*)&out[row * 1024 + n0 + tx * 8 + 4] = o2;
    }
}

// -------- pipelined cooperative recurrence --------
// Grid 64 WGs x 512 thr = 2 stages x (4 groups of 16 batches x 8 WGs of 32 j).
// Waves: js=w&1 (16 j), kq=w>>1 (64-k quarter). Per-thread weights: whh 64 VGPR
// (+ wih 64 if FUSED). Stage 1 consumes stage 0's write-once packed y-stream,
// gated by stage 0's per-step flags (one-directional -> deadlock-free).
// Within-group handshake = round-8's proven flag protocol.
struct SArgs {
    const float* xg4;                 // unfused input (stage A0) or null
    const unsigned int* ypkin;        // fused input stream or null
    const unsigned short* wihhi; const unsigned short* wihlo;
    const float* bsum;
    unsigned int* ypkout; int reluOut;
    const unsigned short* whhhi; const unsigned short* whhlo;
    const float* h_init; const float* c_init;
    float* h_save; float* c_save;
};

template<bool FUSED>
__device__ __forceinline__ void rec_stage(
    const SArgs& a, float4 (*part)[2][4][64],
    unsigned int* hxp, unsigned int* flg_own, const unsigned int* flg_src,
    int gid, int wgm)
{
    const int tid = threadIdx.x;
    const int lane = tid & 63;
    const int w = tid >> 6;
    const int js = w & 1, kq = w >> 1;
    const int l15 = lane & 15, l4 = lane >> 4;
    const int bbase = gid * 16;
    const int jj = wgm * 32 + js * 16 + l15;
    const int bown = bbase + l4 * 4 + kq;

    // persistent weights (k-quarter): whh 16 frags = 64 VGPR; wih same if FUSED
    s16x8 whi[4][2], wlo_[4][2], vhi[4][2], vlo_[4][2];
#pragma unroll
    for (int g = 0; g < 4; ++g) {
        size_t rb = (size_t)(g * 256 + jj) * 256 + kq * 64 + l4 * 8;
#pragma unroll
        for (int kt = 0; kt < 2; ++kt) {
            whi[g][kt]  = *(const s16x8*)(a.whhhi + rb + kt * 32);
            wlo_[g][kt] = *(const s16x8*)(a.whhlo + rb + kt * 32);
            if (FUSED) {
                vhi[g][kt]  = *(const s16x8*)(a.wihhi + rb + kt * 32);
                vlo_[g][kt] = *(const s16x8*)(a.wihlo + rb + kt * 32);
            }
        }
    }
#pragma unroll
    for (int g = 0; g < 4; ++g)
#pragma unroll
        for (int kt = 0; kt < 2; ++kt) {
            asm volatile("" : "+v"(whi[g][kt]));
            asm volatile("" : "+v"(wlo_[g][kt]));
            if (FUSED) {
                asm volatile("" : "+v"(vhi[g][kt]));
                asm volatile("" : "+v"(vlo_[g][kt]));
            }
        }

    float4 bsv = {0.f, 0.f, 0.f, 0.f};
    if (FUSED) bsv = *(const float4*)&a.bsum[jj * 4];

    float hc = 0.f, cc = 0.f;
    if (a.h_init != nullptr) {
        hc = a.h_init[bown * 256 + jj];
        cc = a.c_init[bown * 256 + jj];
    }
    st_llc(&hxp[(size_t)bown * 256 + jj], packhl(hc));
    __syncthreads();   // drain publishes (vmcnt 0 per thread)
    if (tid == 0) st_llc(&flg_own[wgm], 1u);

    for (int t = 0; t < TLEN; ++t) {
        float4 xv = {0.f, 0.f, 0.f, 0.f};
        if (!FUSED)
            xv = *(const float4*)&a.xg4[((size_t)bown * TLEN + t) * 1024 + jj * 4];

        if (tid == 0) {
            const unsigned int tg1 = (unsigned int)(t + 1);
            const unsigned int tg2 = (unsigned int)(t + 2);
            for (;;) {
                u64 f0 = ld_llc8(flg_own + 0), f1 = ld_llc8(flg_own + 2);
                u64 f2 = ld_llc8(flg_own + 4), f3 = ld_llc8(flg_own + 6);
                bool ok = (unsigned int)f0 >= tg1 && (unsigned int)(f0 >> 32) >= tg1 &&
                          (unsigned int)f1 >= tg1 && (unsigned int)(f1 >> 32) >= tg1 &&
                          (unsigned int)f2 >= tg1 && (unsigned int)(f2 >> 32) >= tg1 &&
                          (unsigned int)f3 >= tg1 && (unsigned int)(f3 >> 32) >= tg1;
                if (ok && flg_src != nullptr) {
                    u64 s0 = ld_llc8(flg_src + 0), s1 = ld_llc8(flg_src + 2);
                    u64 s2 = ld_llc8(flg_src + 4), s3 = ld_llc8(flg_src + 6);
                    ok = (unsigned int)s0 >= tg2 && (unsigned int)(s0 >> 32) >= tg2 &&
                         (unsigned int)s1 >= tg2 && (unsigned int)(s1 >> 32) >= tg2 &&
                         (unsigned int)s2 >= tg2 && (unsigned int)(s2 >> 32) >= tg2 &&
                         (unsigned int)s3 >= tg2 && (unsigned int)(s3 >> 32) >= tg2;
                }
                if (ok) break;
                __builtin_amdgcn_s_sleep(1);
            }
        }
        __syncthreads();
        asm volatile("" ::: "memory");

        const unsigned int* hp = hxp + (size_t)(t & 1) * 16384
                                 + (size_t)(bbase + l15) * 256 + kq * 64 + l4 * 8;
        const unsigned int* xp = FUSED
            ? a.ypkin + ((size_t)(bbase + l15) * TLEN + t) * 256 + kq * 64 + l4 * 8
            : nullptr;

        f32x4 aH[4], aC[4];
#pragma unroll
        for (int g = 0; g < 4; ++g) { aH[g] = (f32x4){0,0,0,0}; aC[g] = (f32x4){0,0,0,0}; }

#pragma unroll
        for (int kt = 0; kt < 2; ++kt) {
            s16x8 ah, al;
            unpack_hl(ld_llc8(hp + kt * 32 + 0), ld_llc8(hp + kt * 32 + 2),
                      ld_llc8(hp + kt * 32 + 4), ld_llc8(hp + kt * 32 + 6), ah, al);
#pragma unroll
            for (int g = 0; g < 4; ++g) {
                aH[g] = __builtin_amdgcn_mfma_f32_16x16x32_bf16(ah, whi[g][kt],  aH[g], 0, 0, 0);
                aC[g] = __builtin_amdgcn_mfma_f32_16x16x32_bf16(al, whi[g][kt],  aC[g], 0, 0, 0);
                aC[g] = __builtin_amdgcn_mfma_f32_16x16x32_bf16(ah, wlo_[g][kt], aC[g], 0, 0, 0);
            }
            if (FUSED) {
                s16x8 xh, xl;
                unpack_hl(ld_llc8(xp + kt * 32 + 0), ld_llc8(xp + kt * 32 + 2),
                          ld_llc8(xp + kt * 32 + 4), ld_llc8(xp + kt * 32 + 6), xh, xl);
#pragma unroll
                for (int g = 0; g < 4; ++g) {
                    aH[g] = __builtin_amdgcn_mfma_f32_16x16x32_bf16(xh, vhi[g][kt],  aH[g], 0, 0, 0);
                    aC[g] = __builtin_amdgcn_mfma_f32_16x16x32_bf16(xl, vhi[g][kt],  aC[g], 0, 0, 0);
                    aC[g] = __builtin_amdgcn_mfma_f32_16x16x32_bf16(xh, vlo_[g][kt], aC[g], 0, 0, 0);
                }
            }
        }

        // cross-quarter combine via LDS (barrier 1)
        const int idx = l4 * 16 + l15;
#pragma unroll
        for (int g = 0; g < 4; ++g) {
            f32x4 s = aH[g] + aC[g];
            part[kq][js][g][idx] = (float4){s[0], s[1], s[2], s[3]};
        }
        __syncthreads();

        float4 sum[4];
#pragma unroll
        for (int g = 0; g < 4; ++g) {
            float4 p0 = part[0][js][g][idx];
            float4 p1 = part[1][js][g][idx];
            float4 p2 = part[2][js][g][idx];
            float4 p3 = part[3][js][g][idx];
            sum[g] = (float4){p0.x + p1.x + p2.x + p3.x, p0.y + p1.y + p2.y + p3.y,
                              p0.z + p1.z + p2.z + p3.z, p0.w + p1.w + p2.w + p3.w};
        }
        float si, sf, sgg, soo;
        switch (kq) {   // wave-uniform
            case 0:  si = sum[0].x; sf = sum[1].x; sgg = sum[2].x; soo = sum[3].x; break;
            case 1:  si = sum[0].y; sf = sum[1].y; sgg = sum[2].y; soo = sum[3].y; break;
            case 2:  si = sum[0].z; sf = sum[1].z; sgg = sum[2].z; soo = sum[3].z; break;
            default: si = sum[0].w; sf = sum[1].w; sgg = sum[2].w; soo = sum[3].w; break;
        }
        if (!FUSED) { si += xv.x; sf += xv.y; sgg += xv.z; soo += xv.w; }
        else        { si += bsv.x; sf += bsv.y; sgg += bsv.z; soo += bsv.w; }

        float ig = sig_(si);
        float fg = sig_(sf);
        float gg = tanh_(sgg);
        float og = sig_(soo);
        cc = fmaf(fg, cc, ig * gg);
        hc = og * tanh_(cc);

        size_t pb = (size_t)((t + 1) & 1) * 16384;
        st_llc(&hxp[pb + (size_t)bown * 256 + jj], packhl(hc));
        if (a.ypkout != nullptr) {
            float hv = a.reluOut ? fmaxf(hc, 0.f) : hc;
            st_llc(&a.ypkout[((size_t)bown * TLEN + t) * 256 + jj], packhl(hv));
        }

        __syncthreads();   // barrier 2: drains publishes + protects LDS part WAR
        asm volatile("" ::: "memory");
        if (tid == 0) st_llc(&flg_own[wgm], (unsigned int)(t + 2));
    }

    if (a.h_save != nullptr) a.h_save[bown * 256 + jj] = hc;
    if (a.c_save != nullptr) a.c_save[bown * 256 + jj] = cc;
}

__global__ __launch_bounds__(512, 2) void rec_pipe(SArgs a0, SArgs a1,
                                                   unsigned int* hxp, unsigned int* flg)
{
    __shared__ float4 part[4][2][4][64];   // 32 KB
    const int stage = blockIdx.x >> 5;
    const int sbid  = blockIdx.x & 31;
    const int gid   = sbid & 3;
    const int wgm   = sbid >> 2;
    unsigned int* myhxp = hxp + (size_t)stage * 32768;
    unsigned int* myflg = flg + stage * 32 + gid * 8;
    const unsigned int* srcflg = stage ? (flg + gid * 8) : nullptr;

    if (stage == 0) {
        if (a0.ypkin != nullptr) rec_stage<true >(a0, part, myhxp, myflg, srcflg, gid, wgm);
        else                     rec_stage<false>(a0, part, myhxp, myflg, srcflg, gid, wgm);
    } else {
        rec_stage<true>(a1, part, myhxp, myflg, srcflg, gid, wgm);
    }
}

// -------- head: out[b] = dot(h3T[b], lin_w) + lin_b --------
__global__ __launch_bounds__(256) void head_kernel(const float* __restrict__ h3,
    const float* __restrict__ lin_w, const float* __restrict__ lin_b, float* __restrict__ out)
{
    int b = blockIdx.x;
    int tid = threadIdx.x;
    float v = h3[b * 256 + tid] * lin_w[tid];
#pragma unroll
    for (int o = 32; o > 0; o >>= 1) v += __shfl_down(v, o);
    __shared__ float red[4];
    int wid = tid >> 6, lane = tid & 63;
    if (lane == 0) red[wid] = v;
    __syncthreads();
    if (tid == 0) out[b] = red[0] + red[1] + red[2] + red[3] + lin_b[0];
}

extern "C" void kernel_launch(void* const* d_in, const int* in_sizes, int n_in,
                              void* d_out, int out_size, void* d_ws, size_t ws_size,
                              hipStream_t stream) {
    const float* x = (const float*)d_in[0];
    const float* wih[4] = { (const float*)d_in[1], (const float*)d_in[5], (const float*)d_in[9],  (const float*)d_in[13] };
    const float* whh[4] = { (const float*)d_in[2], (const float*)d_in[6], (const float*)d_in[10], (const float*)d_in[14] };
    const float* bih[4] = { (const float*)d_in[3], (const float*)d_in[7], (const float*)d_in[11], (const float*)d_in[15] };
    const float* bhh[4] = { (const float*)d_in[4], (const float*)d_in[8], (const float*)d_in[12], (const float*)d_in[16] };
    const float* lin_w = (const float*)d_in[17];
    const float* lin_b = (const float*)d_in[18];
    float* ws = (float*)d_ws;

    float* xg4 = ws + OFF_XG;
    unsigned int* y0pk = (unsigned int*)(ws + OFF_Y0PK);
    unsigned int* y1pk = (unsigned int*)(ws + OFF_Y1PK);
    unsigned int* y2pk = (unsigned int*)(ws + OFF_XG);      // aliases xg4 (phase B only)
    float* wihT0 = ws + OFF_WIHT0;
    unsigned short* whhhiB = (unsigned short*)(ws + OFF_WHHHI);
    unsigned short* whhloB = (unsigned short*)(ws + OFF_WHHLO);
    unsigned short* wihhiB = (unsigned short*)(ws + OFF_WIHHI);
    unsigned short* wihloB = (unsigned short*)(ws + OFF_WIHLO);
    float* bsum = ws + OFF_BSUM;
    float* h0T = ws + OFF_STATE;
    float* c0T = h0T + 16384;
    float* h1T = c0T + 16384;
    float* c1T = h1T + 16384;
    float* h3T = c1T + 16384;
    unsigned int* hxp = (unsigned int*)(ws + OFF_HXP);
    unsigned int* flg = (unsigned int*)(ws + OFF_FLG);

    hipMemsetAsync(flg, 0, 128 * sizeof(int), stream);

    // prep: whh splits (4), wih splits (layers 1a,0b,1b), fp32 wihT for 0a, biases
    for (int l = 0; l < 4; ++l)
        prep_split<<<dim3(1024), 256, 0, stream>>>(whh[l], whhhiB + (size_t)l * 262144, whhloB + (size_t)l * 262144);
    for (int l = 1; l < 4; ++l)
        prep_split<<<dim3(1024), 256, 0, stream>>>(wih[l], wihhiB + (size_t)(l - 1) * 262144, wihloB + (size_t)(l - 1) * 262144);
    prep_wih<<<dim3(256), 256, 0, stream>>>(wih[0], wihT0, IDIM);
    for (int l = 0; l < 4; ++l)
        prep_bias<<<dim3(4), 256, 0, stream>>>(bih[l], bhh[l], bsum + l * 1024);

    // xg for layer 0a (includes bias + relu(x))
    proj_kernel<<<dim3(256, 8), 256, 0, stream>>>(x, IDIM, 1, wihT0, bsum + 0, xg4);

    // phase A: L0a (unfused, xg4 -> y0pk stream, save h0T/c0T)
    //       ∥  L1a (fused: y0pk + wih1a -> y1pk stream (relu'd), save h1T/c1T)
    SArgs a0 = { xg4, nullptr, nullptr, nullptr, nullptr,
                 y0pk, 0,
                 whhhiB + 0, whhloB + 0,
                 nullptr, nullptr, h0T, c0T };
    SArgs a1 = { nullptr, y0pk, wihhiB + 0, wihloB + 0, bsum + 1024,
                 y1pk, 1,
                 whhhiB + 262144, whhloB + 262144,
                 nullptr, nullptr, h1T, c1T };
    rec_pipe<<<dim3(64), 512, 0, stream>>>(a0, a1, hxp, flg);

    // phase B: L0b (fused: y1pk + wih0b, init h0T/c0T -> y2pk stream)
    //       ∥  L1b (fused: y2pk + wih1b, init h1T/c1T, save h3T)
    SArgs b0 = { nullptr, y1pk, wihhiB + 262144, wihloB + 262144, bsum + 2048,
                 y2pk, 0,
                 whhhiB + 2 * 262144, whhloB + 2 * 262144,
                 h0T, c0T, nullptr, nullptr };
    SArgs b1 = { nullptr, y2pk, wihhiB + 2 * 262144, wihloB + 2 * 262144, bsum + 3072,
                 nullptr, 0,
                 whhhiB + 3 * 262144, whhloB + 3 * 262144,
                 h1T, c1T, h3T, nullptr };
    rec_pipe<<<dim3(64), 512, 0, stream>>>(b0, b1, hxp, flg + 64);

    head_kernel<<<dim3(BATCH), 256, 0, stream>>>(h3T, lin_w, lin_b, (float*)d_out);
}

// Round 11
// 5917.498 us; speedup vs baseline: 8.8687x; 1.0493x over previous
//
#include <hip/hip_runtime.h>
#include <math.h>

#define HDIM 256
#define BATCH 64
#define TLEN 512
#define IDIM 64

typedef __attribute__((ext_vector_type(8))) short s16x8;
typedef __attribute__((ext_vector_type(4))) float f32x4;
typedef unsigned long long u64;

// ---------------- ws layout (float offsets) ----------------
static const size_t OFF_XG    = 0;                   // phase A: xg4 f32; phase B: y2pk aliased
static const size_t OFF_Y0PK  = 33554432;
static const size_t OFF_Y1PK  = OFF_Y0PK + 8388608;
static const size_t OFF_WIHT0 = OFF_Y1PK + 8388608;
static const size_t OFF_WHHHI = OFF_WIHT0 + 65536;
static const size_t OFF_WHHLO = OFF_WHHHI + 524288;
static const size_t OFF_WIHHI = OFF_WHHLO + 524288;
static const size_t OFF_WIHLO = OFF_WIHHI + 393216;
static const size_t OFF_BSUM  = OFF_WIHLO + 393216;
static const size_t OFF_STATE = OFF_BSUM + 4096;
static const size_t OFF_HXP   = OFF_STATE + 81920;
static const size_t OFF_FLG   = OFF_HXP + 65536;

__device__ __forceinline__ float sig_(float x) { return 1.f / (1.f + __expf(-x)); }
__device__ __forceinline__ float tanh_(float x) { float e = __expf(2.f * x); return 1.f - 2.f / (e + 1.f); }

__device__ __forceinline__ unsigned int packhl(float h) {
    unsigned int u = __float_as_uint(h);
    unsigned int hb = (u + 0x7fffu + ((u >> 16) & 1u)) >> 16;
    float r = h - __uint_as_float(hb << 16);
    unsigned int ur = __float_as_uint(r);
    unsigned int lb = (ur + 0x7fffu + ((ur >> 16) & 1u)) >> 16;
    return (hb << 16) | (lb & 0xffffu);
}

__device__ __forceinline__ void st_llc(unsigned int* p, unsigned int v) {
    __hip_atomic_store(p, v, __ATOMIC_RELAXED, __HIP_MEMORY_SCOPE_AGENT);
}
__device__ __forceinline__ u64 ld_llc8(const unsigned int* p) {
    return __hip_atomic_load((const u64*)p, __ATOMIC_RELAXED, __HIP_MEMORY_SCOPE_AGENT);
}

__device__ __forceinline__ void unpack_hl(u64 q0, u64 q1, u64 q2, u64 q3, s16x8& ah, s16x8& al) {
    unsigned int w0 = (unsigned int)q0, w1 = (unsigned int)(q0 >> 32);
    unsigned int w2 = (unsigned int)q1, w3 = (unsigned int)(q1 >> 32);
    unsigned int w4 = (unsigned int)q2, w5 = (unsigned int)(q2 >> 32);
    unsigned int w6 = (unsigned int)q3, w7 = (unsigned int)(q3 >> 32);
    union { unsigned int u[4]; s16x8 v; } H, L;
    H.u[0] = (w0 >> 16) | (w1 & 0xffff0000u);
    H.u[1] = (w2 >> 16) | (w3 & 0xffff0000u);
    H.u[2] = (w4 >> 16) | (w5 & 0xffff0000u);
    H.u[3] = (w6 >> 16) | (w7 & 0xffff0000u);
    L.u[0] = (w0 & 0xffffu) | (w1 << 16);
    L.u[1] = (w2 & 0xffffu) | (w3 << 16);
    L.u[2] = (w4 & 0xffffu) | (w5 << 16);
    L.u[3] = (w6 & 0xffffu) | (w7 << 16);
    ah = H.v; al = L.v;
}

// -------- prep --------
__global__ void prep_wih(const float* __restrict__ w, float* __restrict__ wt, int K) {
    int idx = blockIdx.x * 256 + threadIdx.x;
    if (idx >= 1024 * K) return;
    int n = idx / K, k = idx - n * K;
    int j = n >> 2, g = n & 3;
    wt[idx] = w[(g * 256 + j) * K + k];
}

__global__ void prep_split(const float* __restrict__ w,
                           unsigned short* __restrict__ hi, unsigned short* __restrict__ lo) {
    int idx = blockIdx.x * 256 + threadIdx.x;
    float v = w[idx];
    unsigned int u = __float_as_uint(v);
    unsigned int hb = (u + 0x7fffu + ((u >> 16) & 1u)) >> 16;
    float r = v - __uint_as_float(hb << 16);
    unsigned int ur = __float_as_uint(r);
    unsigned int lb = (ur + 0x7fffu + ((ur >> 16) & 1u)) >> 16;
    hi[idx] = (unsigned short)hb;
    lo[idx] = (unsigned short)lb;
}

__global__ void prep_bias(const float* __restrict__ bi, const float* __restrict__ bh,
                          float* __restrict__ bs) {
    int n = blockIdx.x * 256 + threadIdx.x;
    int j = n >> 2, g = n & 3;
    bs[n] = bi[g * 256 + j] + bh[g * 256 + j];
}

// -------- projection GEMM (proven; layer 0a only, K=64) --------
__global__ __launch_bounds__(256) void proj_kernel(
    const float* __restrict__ A, int K, int doRelu,
    const float* __restrict__ Wt, const float* __restrict__ bsum,
    float* __restrict__ out)
{
    __shared__ float As[16][128];
    __shared__ float Bs[16][128];
    const int tid = threadIdx.x;
    const int m0 = blockIdx.x * 128;
    const int n0 = blockIdx.y * 128;
    const int tx = tid & 15, ty = tid >> 4;

    float acc[8][8];
#pragma unroll
    for (int i = 0; i < 8; ++i)
#pragma unroll
        for (int j = 0; j < 8; ++j) acc[i][j] = 0.f;

    for (int kt = 0; kt < K; kt += 16) {
#pragma unroll
        for (int l = 0; l < 2; ++l) {
            int f = tid * 2 + l;
            int r = f >> 2;
            int c = (f & 3) << 2;
            float4 v = *(const float4*)&A[(size_t)(m0 + r) * K + kt + c];
            if (doRelu) {
                v.x = fmaxf(v.x, 0.f); v.y = fmaxf(v.y, 0.f);
                v.z = fmaxf(v.z, 0.f); v.w = fmaxf(v.w, 0.f);
            }
            As[c + 0][r] = v.x; As[c + 1][r] = v.y; As[c + 2][r] = v.z; As[c + 3][r] = v.w;
            float4 w = *(const float4*)&Wt[(size_t)(n0 + r) * K + kt + c];
            Bs[c + 0][r] = w.x; Bs[c + 1][r] = w.y; Bs[c + 2][r] = w.z; Bs[c + 3][r] = w.w;
        }
        __syncthreads();
#pragma unroll
        for (int kk = 0; kk < 16; ++kk) {
            float a[8], bb[8];
            *(float4*)&a[0]  = *(const float4*)&As[kk][ty * 8];
            *(float4*)&a[4]  = *(const float4*)&As[kk][ty * 8 + 4];
            *(float4*)&bb[0] = *(const float4*)&Bs[kk][tx * 8];
            *(float4*)&bb[4] = *(const float4*)&Bs[kk][tx * 8 + 4];
#pragma unroll
            for (int i = 0; i < 8; ++i)
#pragma unroll
                for (int j = 0; j < 8; ++j) acc[i][j] = fmaf(a[i], bb[j], acc[i][j]);
        }
        __syncthreads();
    }

    float bsv[8];
#pragma unroll
    for (int j = 0; j < 8; ++j) bsv[j] = bsum[n0 + tx * 8 + j];
#pragma unroll
    for (int i = 0; i < 8; ++i) {
        size_t row = (size_t)(m0 + ty * 8 + i);
        float4 o1 = { acc[i][0] + bsv[0], acc[i][1] + bsv[1], acc[i][2] + bsv[2], acc[i][3] + bsv[3] };
        float4 o2 = { acc[i][4] + bsv[4], acc[i][5] + bsv[5], acc[i][6] + bsv[6], acc[i][7] + bsv[7] };
        *(float4*)&out[row * 1024 + n0 + tx * 8]     = o1;
        *(float4*)&out[row * 1024 + n0 + tx * 8 + 4] = o2;
    }
}

// -------- pipelined cooperative recurrence (round-10 proven structure) --------
// Changes vs round 10: (1) LDS 'part' re-laid out scalar [kq][js][g][r][idx] ->
// conflict-free (was 8-way on float4); reader picks component kq directly.
// (2) all h/x LLC loads batched into registers before unpack+MFMA.
// Sync protocol UNCHANGED (proven).
struct SArgs {
    const float* xg4;
    const unsigned int* ypkin;
    const unsigned short* wihhi; const unsigned short* wihlo;
    const float* bsum;
    unsigned int* ypkout; int reluOut;
    const unsigned short* whhhi; const unsigned short* whhlo;
    const float* h_init; const float* c_init;
    float* h_save; float* c_save;
};

template<bool FUSED>
__device__ __forceinline__ void rec_stage(
    const SArgs& a, float (*part)[2][4][4][64],
    unsigned int* hxp, unsigned int* flg_own, const unsigned int* flg_src,
    int gid, int wgm)
{
    const int tid = threadIdx.x;
    const int lane = tid & 63;
    const int w = tid >> 6;
    const int js = w & 1, kq = w >> 1;
    const int l15 = lane & 15, l4 = lane >> 4;
    const int bbase = gid * 16;
    const int jj = wgm * 32 + js * 16 + l15;
    const int bown = bbase + l4 * 4 + kq;

    // persistent weights (k-quarter): whh 16 frags = 64 VGPR; wih same if FUSED
    s16x8 whi[4][2], wlo_[4][2], vhi[4][2], vlo_[4][2];
#pragma unroll
    for (int g = 0; g < 4; ++g) {
        size_t rb = (size_t)(g * 256 + jj) * 256 + kq * 64 + l4 * 8;
#pragma unroll
        for (int kt = 0; kt < 2; ++kt) {
            whi[g][kt]  = *(const s16x8*)(a.whhhi + rb + kt * 32);
            wlo_[g][kt] = *(const s16x8*)(a.whhlo + rb + kt * 32);
            if (FUSED) {
                vhi[g][kt]  = *(const s16x8*)(a.wihhi + rb + kt * 32);
                vlo_[g][kt] = *(const s16x8*)(a.wihlo + rb + kt * 32);
            }
        }
    }
#pragma unroll
    for (int g = 0; g < 4; ++g)
#pragma unroll
        for (int kt = 0; kt < 2; ++kt) {
            asm volatile("" : "+v"(whi[g][kt]));
            asm volatile("" : "+v"(wlo_[g][kt]));
            if (FUSED) {
                asm volatile("" : "+v"(vhi[g][kt]));
                asm volatile("" : "+v"(vlo_[g][kt]));
            }
        }

    float4 bsv = {0.f, 0.f, 0.f, 0.f};
    if (FUSED) bsv = *(const float4*)&a.bsum[jj * 4];

    float hc = 0.f, cc = 0.f;
    if (a.h_init != nullptr) {
        hc = a.h_init[bown * 256 + jj];
        cc = a.c_init[bown * 256 + jj];
    }
    st_llc(&hxp[(size_t)bown * 256 + jj], packhl(hc));
    __syncthreads();
    if (tid == 0) st_llc(&flg_own[wgm], 1u);

    for (int t = 0; t < TLEN; ++t) {
        float4 xv = {0.f, 0.f, 0.f, 0.f};
        if (!FUSED)
            xv = *(const float4*)&a.xg4[((size_t)bown * TLEN + t) * 1024 + jj * 4];

        if (tid == 0) {
            const unsigned int tg1 = (unsigned int)(t + 1);
            const unsigned int tg2 = (unsigned int)(t + 2);
            for (;;) {
                u64 f0 = ld_llc8(flg_own + 0), f1 = ld_llc8(flg_own + 2);
                u64 f2 = ld_llc8(flg_own + 4), f3 = ld_llc8(flg_own + 6);
                bool ok = (unsigned int)f0 >= tg1 && (unsigned int)(f0 >> 32) >= tg1 &&
                          (unsigned int)f1 >= tg1 && (unsigned int)(f1 >> 32) >= tg1 &&
                          (unsigned int)f2 >= tg1 && (unsigned int)(f2 >> 32) >= tg1 &&
                          (unsigned int)f3 >= tg1 && (unsigned int)(f3 >> 32) >= tg1;
                if (ok && flg_src != nullptr) {
                    u64 s0 = ld_llc8(flg_src + 0), s1 = ld_llc8(flg_src + 2);
                    u64 s2 = ld_llc8(flg_src + 4), s3 = ld_llc8(flg_src + 6);
                    ok = (unsigned int)s0 >= tg2 && (unsigned int)(s0 >> 32) >= tg2 &&
                         (unsigned int)s1 >= tg2 && (unsigned int)(s1 >> 32) >= tg2 &&
                         (unsigned int)s2 >= tg2 && (unsigned int)(s2 >> 32) >= tg2 &&
                         (unsigned int)s3 >= tg2 && (unsigned int)(s3 >> 32) >= tg2;
                }
                if (ok) break;
                __builtin_amdgcn_s_sleep(1);
            }
        }
        __syncthreads();
        asm volatile("" ::: "memory");

        const unsigned int* hp = hxp + (size_t)(t & 1) * 16384
                                 + (size_t)(bbase + l15) * 256 + kq * 64 + l4 * 8;
        const unsigned int* xp = FUSED
            ? a.ypkin + ((size_t)(bbase + l15) * TLEN + t) * 256 + kq * 64 + l4 * 8
            : nullptr;

        // batch ALL LLC loads first (latency of chunk 2 rides chunk 1)
        u64 qh[8], qx[8];
#pragma unroll
        for (int kt = 0; kt < 2; ++kt) {
            qh[kt * 4 + 0] = ld_llc8(hp + kt * 32 + 0);
            qh[kt * 4 + 1] = ld_llc8(hp + kt * 32 + 2);
            qh[kt * 4 + 2] = ld_llc8(hp + kt * 32 + 4);
            qh[kt * 4 + 3] = ld_llc8(hp + kt * 32 + 6);
        }
        if (FUSED) {
#pragma unroll
            for (int kt = 0; kt < 2; ++kt) {
                qx[kt * 4 + 0] = ld_llc8(xp + kt * 32 + 0);
                qx[kt * 4 + 1] = ld_llc8(xp + kt * 32 + 2);
                qx[kt * 4 + 2] = ld_llc8(xp + kt * 32 + 4);
                qx[kt * 4 + 3] = ld_llc8(xp + kt * 32 + 6);
            }
        }

        f32x4 aH[4], aC[4];
#pragma unroll
        for (int g = 0; g < 4; ++g) { aH[g] = (f32x4){0,0,0,0}; aC[g] = (f32x4){0,0,0,0}; }

#pragma unroll
        for (int kt = 0; kt < 2; ++kt) {
            s16x8 ah, al;
            unpack_hl(qh[kt * 4 + 0], qh[kt * 4 + 1], qh[kt * 4 + 2], qh[kt * 4 + 3], ah, al);
#pragma unroll
            for (int g = 0; g < 4; ++g) {
                aH[g] = __builtin_amdgcn_mfma_f32_16x16x32_bf16(ah, whi[g][kt],  aH[g], 0, 0, 0);
                aC[g] = __builtin_amdgcn_mfma_f32_16x16x32_bf16(al, whi[g][kt],  aC[g], 0, 0, 0);
                aC[g] = __builtin_amdgcn_mfma_f32_16x16x32_bf16(ah, wlo_[g][kt], aC[g], 0, 0, 0);
            }
            if (FUSED) {
                s16x8 xh, xl;
                unpack_hl(qx[kt * 4 + 0], qx[kt * 4 + 1], qx[kt * 4 + 2], qx[kt * 4 + 3], xh, xl);
#pragma unroll
                for (int g = 0; g < 4; ++g) {
                    aH[g] = __builtin_amdgcn_mfma_f32_16x16x32_bf16(xh, vhi[g][kt],  aH[g], 0, 0, 0);
                    aC[g] = __builtin_amdgcn_mfma_f32_16x16x32_bf16(xl, vhi[g][kt],  aC[g], 0, 0, 0);
                    aC[g] = __builtin_amdgcn_mfma_f32_16x16x32_bf16(xh, vlo_[g][kt], aC[g], 0, 0, 0);
                }
            }
        }

        // cross-quarter combine via LDS, scalar conflict-free layout (barrier 1)
        const int idx = l4 * 16 + l15;
#pragma unroll
        for (int g = 0; g < 4; ++g) {
            f32x4 s = aH[g] + aC[g];
#pragma unroll
            for (int r = 0; r < 4; ++r)
                part[kq][js][g][r][idx] = s[r];
        }
        __syncthreads();

        // reader: component = own kq, idx = own (l4,l15): lanes consecutive -> no conflict
        float si  = part[0][js][0][kq][idx] + part[1][js][0][kq][idx]
                  + part[2][js][0][kq][idx] + part[3][js][0][kq][idx];
        float sf  = part[0][js][1][kq][idx] + part[1][js][1][kq][idx]
                  + part[2][js][1][kq][idx] + part[3][js][1][kq][idx];
        float sgg = part[0][js][2][kq][idx] + part[1][js][2][kq][idx]
                  + part[2][js][2][kq][idx] + part[3][js][2][kq][idx];
        float soo = part[0][js][3][kq][idx] + part[1][js][3][kq][idx]
                  + part[2][js][3][kq][idx] + part[3][js][3][kq][idx];

        if (!FUSED) { si += xv.x; sf += xv.y; sgg += xv.z; soo += xv.w; }
        else        { si += bsv.x; sf += bsv.y; sgg += bsv.z; soo += bsv.w; }

        float ig = sig_(si);
        float fg = sig_(sf);
        float gg = tanh_(sgg);
        float og = sig_(soo);
        cc = fmaf(fg, cc, ig * gg);
        hc = og * tanh_(cc);

        size_t pb = (size_t)((t + 1) & 1) * 16384;
        st_llc(&hxp[pb + (size_t)bown * 256 + jj], packhl(hc));
        if (a.ypkout != nullptr) {
            float hv = a.reluOut ? fmaxf(hc, 0.f) : hc;
            st_llc(&a.ypkout[((size_t)bown * TLEN + t) * 256 + jj], packhl(hv));
        }

        __syncthreads();   // barrier 2: drains publishes + LDS part WAR
        asm volatile("" ::: "memory");
        if (tid == 0) st_llc(&flg_own[wgm], (unsigned int)(t + 2));
    }

    if (a.h_save != nullptr) a.h_save[bown * 256 + jj] = hc;
    if (a.c_save != nullptr) a.c_save[bown * 256 + jj] = cc;
}

__global__ __launch_bounds__(512, 2) void rec_pipe(SArgs a0, SArgs a1,
                                                   unsigned int* hxp, unsigned int* flg)
{
    __shared__ float part[4][2][4][4][64];   // 32 KB, scalar conflict-free
    const int stage = blockIdx.x >> 5;
    const int sbid  = blockIdx.x & 31;
    const int gid   = sbid & 3;
    const int wgm   = sbid >> 2;
    unsigned int* myhxp = hxp + (size_t)stage * 32768;
    unsigned int* myflg = flg + stage * 32 + gid * 8;
    const unsigned int* srcflg = stage ? (flg + gid * 8) : nullptr;

    if (stage == 0) {
        if (a0.ypkin != nullptr) rec_stage<true >(a0, part, myhxp, myflg, srcflg, gid, wgm);
        else                     rec_stage<false>(a0, part, myhxp, myflg, srcflg, gid, wgm);
    } else {
        rec_stage<true>(a1, part, myhxp, myflg, srcflg, gid, wgm);
    }
}

// -------- head --------
__global__ __launch_bounds__(256) void head_kernel(const float* __restrict__ h3,
    const float* __restrict__ lin_w, const float* __restrict__ lin_b, float* __restrict__ out)
{
    int b = blockIdx.x;
    int tid = threadIdx.x;
    float v = h3[b * 256 + tid] * lin_w[tid];
#pragma unroll
    for (int o = 32; o > 0; o >>= 1) v += __shfl_down(v, o);
    __shared__ float red[4];
    int wid = tid >> 6, lane = tid & 63;
    if (lane == 0) red[wid] = v;
    __syncthreads();
    if (tid == 0) out[b] = red[0] + red[1] + red[2] + red[3] + lin_b[0];
}

extern "C" void kernel_launch(void* const* d_in, const int* in_sizes, int n_in,
                              void* d_out, int out_size, void* d_ws, size_t ws_size,
                              hipStream_t stream) {
    const float* x = (const float*)d_in[0];
    const float* wih[4] = { (const float*)d_in[1], (const float*)d_in[5], (const float*)d_in[9],  (const float*)d_in[13] };
    const float* whh[4] = { (const float*)d_in[2], (const float*)d_in[6], (const float*)d_in[10], (const float*)d_in[14] };
    const float* bih[4] = { (const float*)d_in[3], (const float*)d_in[7], (const float*)d_in[11], (const float*)d_in[15] };
    const float* bhh[4] = { (const float*)d_in[4], (const float*)d_in[8], (const float*)d_in[12], (const float*)d_in[16] };
    const float* lin_w = (const float*)d_in[17];
    const float* lin_b = (const float*)d_in[18];
    float* ws = (float*)d_ws;

    float* xg4 = ws + OFF_XG;
    unsigned int* y0pk = (unsigned int*)(ws + OFF_Y0PK);
    unsigned int* y1pk = (unsigned int*)(ws + OFF_Y1PK);
    unsigned int* y2pk = (unsigned int*)(ws + OFF_XG);
    float* wihT0 = ws + OFF_WIHT0;
    unsigned short* whhhiB = (unsigned short*)(ws + OFF_WHHHI);
    unsigned short* whhloB = (unsigned short*)(ws + OFF_WHHLO);
    unsigned short* wihhiB = (unsigned short*)(ws + OFF_WIHHI);
    unsigned short* wihloB = (unsigned short*)(ws + OFF_WIHLO);
    float* bsum = ws + OFF_BSUM;
    float* h0T = ws + OFF_STATE;
    float* c0T = h0T + 16384;
    float* h1T = c0T + 16384;
    float* c1T = h1T + 16384;
    float* h3T = c1T + 16384;
    unsigned int* hxp = (unsigned int*)(ws + OFF_HXP);
    unsigned int* flg = (unsigned int*)(ws + OFF_FLG);

    hipMemsetAsync(flg, 0, 128 * sizeof(int), stream);

    for (int l = 0; l < 4; ++l)
        prep_split<<<dim3(1024), 256, 0, stream>>>(whh[l], whhhiB + (size_t)l * 262144, whhloB + (size_t)l * 262144);
    for (int l = 1; l < 4; ++l)
        prep_split<<<dim3(1024), 256, 0, stream>>>(wih[l], wihhiB + (size_t)(l - 1) * 262144, wihloB + (size_t)(l - 1) * 262144);
    prep_wih<<<dim3(256), 256, 0, stream>>>(wih[0], wihT0, IDIM);
    for (int l = 0; l < 4; ++l)
        prep_bias<<<dim3(4), 256, 0, stream>>>(bih[l], bhh[l], bsum + l * 1024);

    proj_kernel<<<dim3(256, 8), 256, 0, stream>>>(x, IDIM, 1, wihT0, bsum + 0, xg4);

    SArgs a0 = { xg4, nullptr, nullptr, nullptr, nullptr,
                 y0pk, 0,
                 whhhiB + 0, whhloB + 0,
                 nullptr, nullptr, h0T, c0T };
    SArgs a1 = { nullptr, y0pk, wihhiB + 0, wihloB + 0, bsum + 1024,
                 y1pk, 1,
                 whhhiB + 262144, whhloB + 262144,
                 nullptr, nullptr, h1T, c1T };
    rec_pipe<<<dim3(64), 512, 0, stream>>>(a0, a1, hxp, flg);

    SArgs b0 = { nullptr, y1pk, wihhiB + 262144, wihloB + 262144, bsum + 2048,
                 y2pk, 0,
                 whhhiB + 2 * 262144, whhloB + 2 * 262144,
                 h0T, c0T, nullptr, nullptr };
    SArgs b1 = { nullptr, y2pk, wihhiB + 2 * 262144, wihloB + 2 * 262144, bsum + 3072,
                 nullptr, 0,
                 whhhiB + 3 * 262144, whhloB + 3 * 262144,
                 h1T, c1T, h3T, nullptr };
    rec_pipe<<<dim3(64), 512, 0, stream>>>(b0, b1, hxp, flg + 64);

    head_kernel<<<dim3(BATCH), 256, 0, stream>>>(h3T, lin_w, lin_b, (float*)d_out);
}

// Round 12
// 5782.335 us; speedup vs baseline: 9.0760x; 1.0234x over previous
//
#include <hip/hip_runtime.h>
#include <math.h>

#define HDIM 256
#define BATCH 64
#define TLEN 512
#define IDIM 64

typedef __attribute__((ext_vector_type(8))) short s16x8;
typedef __attribute__((ext_vector_type(4))) float f32x4;
typedef unsigned long long u64;

// AGPR pin: force value into the accumulator register file (second 256-reg
// file; MFMA reads A/B operands from AGPR directly). Re-asserted each step so
// the allocator never spills weights to scratch.
#define PIN_A(x) asm volatile("" : "+a"(x))

// ---------------- ws layout (float offsets) ----------------
static const size_t OFF_XG    = 0;                   // phase A: xg4 f32; phase B: y2pk aliased
static const size_t OFF_Y0PK  = 33554432;
static const size_t OFF_Y1PK  = OFF_Y0PK + 8388608;
static const size_t OFF_WIHT0 = OFF_Y1PK + 8388608;
static const size_t OFF_WHHHI = OFF_WIHT0 + 65536;
static const size_t OFF_WHHLO = OFF_WHHHI + 524288;
static const size_t OFF_WIHHI = OFF_WHHLO + 524288;
static const size_t OFF_WIHLO = OFF_WIHHI + 393216;
static const size_t OFF_BSUM  = OFF_WIHLO + 393216;
static const size_t OFF_STATE = OFF_BSUM + 4096;
static const size_t OFF_HXP   = OFF_STATE + 81920;
static const size_t OFF_FLG   = OFF_HXP + 65536;

__device__ __forceinline__ float sig_(float x) { return 1.f / (1.f + __expf(-x)); }
__device__ __forceinline__ float tanh_(float x) { float e = __expf(2.f * x); return 1.f - 2.f / (e + 1.f); }

__device__ __forceinline__ unsigned int packhl(float h) {
    unsigned int u = __float_as_uint(h);
    unsigned int hb = (u + 0x7fffu + ((u >> 16) & 1u)) >> 16;
    float r = h - __uint_as_float(hb << 16);
    unsigned int ur = __float_as_uint(r);
    unsigned int lb = (ur + 0x7fffu + ((ur >> 16) & 1u)) >> 16;
    return (hb << 16) | (lb & 0xffffu);
}

__device__ __forceinline__ void st_llc(unsigned int* p, unsigned int v) {
    __hip_atomic_store(p, v, __ATOMIC_RELAXED, __HIP_MEMORY_SCOPE_AGENT);
}
__device__ __forceinline__ u64 ld_llc8(const unsigned int* p) {
    return __hip_atomic_load((const u64*)p, __ATOMIC_RELAXED, __HIP_MEMORY_SCOPE_AGENT);
}

__device__ __forceinline__ void unpack_hl(u64 q0, u64 q1, u64 q2, u64 q3, s16x8& ah, s16x8& al) {
    unsigned int w0 = (unsigned int)q0, w1 = (unsigned int)(q0 >> 32);
    unsigned int w2 = (unsigned int)q1, w3 = (unsigned int)(q1 >> 32);
    unsigned int w4 = (unsigned int)q2, w5 = (unsigned int)(q2 >> 32);
    unsigned int w6 = (unsigned int)q3, w7 = (unsigned int)(q3 >> 32);
    union { unsigned int u[4]; s16x8 v; } H, L;
    H.u[0] = (w0 >> 16) | (w1 & 0xffff0000u);
    H.u[1] = (w2 >> 16) | (w3 & 0xffff0000u);
    H.u[2] = (w4 >> 16) | (w5 & 0xffff0000u);
    H.u[3] = (w6 >> 16) | (w7 & 0xffff0000u);
    L.u[0] = (w0 & 0xffffu) | (w1 << 16);
    L.u[1] = (w2 & 0xffffu) | (w3 << 16);
    L.u[2] = (w4 & 0xffffu) | (w5 << 16);
    L.u[3] = (w6 & 0xffffu) | (w7 << 16);
    ah = H.v; al = L.v;
}

// -------- prep --------
__global__ void prep_wih(const float* __restrict__ w, float* __restrict__ wt, int K) {
    int idx = blockIdx.x * 256 + threadIdx.x;
    if (idx >= 1024 * K) return;
    int n = idx / K, k = idx - n * K;
    int j = n >> 2, g = n & 3;
    wt[idx] = w[(g * 256 + j) * K + k];
}

__global__ void prep_split(const float* __restrict__ w,
                           unsigned short* __restrict__ hi, unsigned short* __restrict__ lo) {
    int idx = blockIdx.x * 256 + threadIdx.x;
    float v = w[idx];
    unsigned int u = __float_as_uint(v);
    unsigned int hb = (u + 0x7fffu + ((u >> 16) & 1u)) >> 16;
    float r = v - __uint_as_float(hb << 16);
    unsigned int ur = __float_as_uint(r);
    unsigned int lb = (ur + 0x7fffu + ((ur >> 16) & 1u)) >> 16;
    hi[idx] = (unsigned short)hb;
    lo[idx] = (unsigned short)lb;
}

__global__ void prep_bias(const float* __restrict__ bi, const float* __restrict__ bh,
                          float* __restrict__ bs) {
    int n = blockIdx.x * 256 + threadIdx.x;
    int j = n >> 2, g = n & 3;
    bs[n] = bi[g * 256 + j] + bh[g * 256 + j];
}

// -------- projection GEMM (proven; layer 0a only, K=64) --------
__global__ __launch_bounds__(256) void proj_kernel(
    const float* __restrict__ A, int K, int doRelu,
    const float* __restrict__ Wt, const float* __restrict__ bsum,
    float* __restrict__ out)
{
    __shared__ float As[16][128];
    __shared__ float Bs[16][128];
    const int tid = threadIdx.x;
    const int m0 = blockIdx.x * 128;
    const int n0 = blockIdx.y * 128;
    const int tx = tid & 15, ty = tid >> 4;

    float acc[8][8];
#pragma unroll
    for (int i = 0; i < 8; ++i)
#pragma unroll
        for (int j = 0; j < 8; ++j) acc[i][j] = 0.f;

    for (int kt = 0; kt < K; kt += 16) {
#pragma unroll
        for (int l = 0; l < 2; ++l) {
            int f = tid * 2 + l;
            int r = f >> 2;
            int c = (f & 3) << 2;
            float4 v = *(const float4*)&A[(size_t)(m0 + r) * K + kt + c];
            if (doRelu) {
                v.x = fmaxf(v.x, 0.f); v.y = fmaxf(v.y, 0.f);
                v.z = fmaxf(v.z, 0.f); v.w = fmaxf(v.w, 0.f);
            }
            As[c + 0][r] = v.x; As[c + 1][r] = v.y; As[c + 2][r] = v.z; As[c + 3][r] = v.w;
            float4 w = *(const float4*)&Wt[(size_t)(n0 + r) * K + kt + c];
            Bs[c + 0][r] = w.x; Bs[c + 1][r] = w.y; Bs[c + 2][r] = w.z; Bs[c + 3][r] = w.w;
        }
        __syncthreads();
#pragma unroll
        for (int kk = 0; kk < 16; ++kk) {
            float a[8], bb[8];
            *(float4*)&a[0]  = *(const float4*)&As[kk][ty * 8];
            *(float4*)&a[4]  = *(const float4*)&As[kk][ty * 8 + 4];
            *(float4*)&bb[0] = *(const float4*)&Bs[kk][tx * 8];
            *(float4*)&bb[4] = *(const float4*)&Bs[kk][tx * 8 + 4];
#pragma unroll
            for (int i = 0; i < 8; ++i)
#pragma unroll
                for (int j = 0; j < 8; ++j) acc[i][j] = fmaf(a[i], bb[j], acc[i][j]);
        }
        __syncthreads();
    }

    float bsv[8];
#pragma unroll
    for (int j = 0; j < 8; ++j) bsv[j] = bsum[n0 + tx * 8 + j];
#pragma unroll
    for (int i = 0; i < 8; ++i) {
        size_t row = (size_t)(m0 + ty * 8 + i);
        float4 o1 = { acc[i][0] + bsv[0], acc[i][1] + bsv[1], acc[i][2] + bsv[2], acc[i][3] + bsv[3] };
        float4 o2 = { acc[i][4] + bsv[4], acc[i][5] + bsv[5], acc[i][6] + bsv[6], acc[i][7] + bsv[7] };
        *(float4*)&out[row * 1024 + n0 + tx * 8]     = o1;
        *(float4*)&out[row * 1024 + n0 + tx * 8 + 4] = o2;
    }
}

// -------- pipelined cooperative recurrence (round-11 proven structure) --------
// Round-12 changes ONLY: (1) weights pinned to AGPRs (PIN_A, re-asserted per
// step) -> no scratch spill/re-stream; MFMA reads B from AGPR directly.
// (2) __launch_bounds__(512, 1): relaxed register budget + 1 WG/CU (no L2-port
// sharing between co-resident WGs). Protocol/geometry byte-identical.
struct SArgs {
    const float* xg4;
    const unsigned int* ypkin;
    const unsigned short* wihhi; const unsigned short* wihlo;
    const float* bsum;
    unsigned int* ypkout; int reluOut;
    const unsigned short* whhhi; const unsigned short* whhlo;
    const float* h_init; const float* c_init;
    float* h_save; float* c_save;
};

template<bool FUSED>
__device__ __forceinline__ void rec_stage(
    const SArgs& a, float (*part)[2][4][4][64],
    unsigned int* hxp, unsigned int* flg_own, const unsigned int* flg_src,
    int gid, int wgm)
{
    const int tid = threadIdx.x;
    const int lane = tid & 63;
    const int w = tid >> 6;
    const int js = w & 1, kq = w >> 1;
    const int l15 = lane & 15, l4 = lane >> 4;
    const int bbase = gid * 16;
    const int jj = wgm * 32 + js * 16 + l15;
    const int bown = bbase + l4 * 4 + kq;

    // persistent weights (k-quarter): whh 16 frags; wih 16 if FUSED. AGPR-pinned.
    s16x8 whi[4][2], wlo_[4][2], vhi[4][2], vlo_[4][2];
#pragma unroll
    for (int g = 0; g < 4; ++g) {
        size_t rb = (size_t)(g * 256 + jj) * 256 + kq * 64 + l4 * 8;
#pragma unroll
        for (int kt = 0; kt < 2; ++kt) {
            whi[g][kt]  = *(const s16x8*)(a.whhhi + rb + kt * 32);
            wlo_[g][kt] = *(const s16x8*)(a.whhlo + rb + kt * 32);
            if (FUSED) {
                vhi[g][kt]  = *(const s16x8*)(a.wihhi + rb + kt * 32);
                vlo_[g][kt] = *(const s16x8*)(a.wihlo + rb + kt * 32);
            }
        }
    }
#pragma unroll
    for (int g = 0; g < 4; ++g)
#pragma unroll
        for (int kt = 0; kt < 2; ++kt) {
            PIN_A(whi[g][kt]);
            PIN_A(wlo_[g][kt]);
            if (FUSED) { PIN_A(vhi[g][kt]); PIN_A(vlo_[g][kt]); }
        }

    float4 bsv = {0.f, 0.f, 0.f, 0.f};
    if (FUSED) bsv = *(const float4*)&a.bsum[jj * 4];

    float hc = 0.f, cc = 0.f;
    if (a.h_init != nullptr) {
        hc = a.h_init[bown * 256 + jj];
        cc = a.c_init[bown * 256 + jj];
    }
    st_llc(&hxp[(size_t)bown * 256 + jj], packhl(hc));
    __syncthreads();
    if (tid == 0) st_llc(&flg_own[wgm], 1u);

    for (int t = 0; t < TLEN; ++t) {
        // re-assert AGPR residency each step (no-op instruction-wise; pins alloc)
#pragma unroll
        for (int g = 0; g < 4; ++g)
#pragma unroll
            for (int kt = 0; kt < 2; ++kt) {
                PIN_A(whi[g][kt]);
                PIN_A(wlo_[g][kt]);
                if (FUSED) { PIN_A(vhi[g][kt]); PIN_A(vlo_[g][kt]); }
            }

        float4 xv = {0.f, 0.f, 0.f, 0.f};
        if (!FUSED)
            xv = *(const float4*)&a.xg4[((size_t)bown * TLEN + t) * 1024 + jj * 4];

        if (tid == 0) {
            const unsigned int tg1 = (unsigned int)(t + 1);
            const unsigned int tg2 = (unsigned int)(t + 2);
            for (;;) {
                u64 f0 = ld_llc8(flg_own + 0), f1 = ld_llc8(flg_own + 2);
                u64 f2 = ld_llc8(flg_own + 4), f3 = ld_llc8(flg_own + 6);
                bool ok = (unsigned int)f0 >= tg1 && (unsigned int)(f0 >> 32) >= tg1 &&
                          (unsigned int)f1 >= tg1 && (unsigned int)(f1 >> 32) >= tg1 &&
                          (unsigned int)f2 >= tg1 && (unsigned int)(f2 >> 32) >= tg1 &&
                          (unsigned int)f3 >= tg1 && (unsigned int)(f3 >> 32) >= tg1;
                if (ok && flg_src != nullptr) {
                    u64 s0 = ld_llc8(flg_src + 0), s1 = ld_llc8(flg_src + 2);
                    u64 s2 = ld_llc8(flg_src + 4), s3 = ld_llc8(flg_src + 6);
                    ok = (unsigned int)s0 >= tg2 && (unsigned int)(s0 >> 32) >= tg2 &&
                         (unsigned int)s1 >= tg2 && (unsigned int)(s1 >> 32) >= tg2 &&
                         (unsigned int)s2 >= tg2 && (unsigned int)(s2 >> 32) >= tg2 &&
                         (unsigned int)s3 >= tg2 && (unsigned int)(s3 >> 32) >= tg2;
                }
                if (ok) break;
                __builtin_amdgcn_s_sleep(1);
            }
        }
        __syncthreads();
        asm volatile("" ::: "memory");

        const unsigned int* hp = hxp + (size_t)(t & 1) * 16384
                                 + (size_t)(bbase + l15) * 256 + kq * 64 + l4 * 8;
        const unsigned int* xp = FUSED
            ? a.ypkin + ((size_t)(bbase + l15) * TLEN + t) * 256 + kq * 64 + l4 * 8
            : nullptr;

        // batch ALL LLC loads first (latencies overlap)
        u64 qh[8], qx[8];
#pragma unroll
        for (int kt = 0; kt < 2; ++kt) {
            qh[kt * 4 + 0] = ld_llc8(hp + kt * 32 + 0);
            qh[kt * 4 + 1] = ld_llc8(hp + kt * 32 + 2);
            qh[kt * 4 + 2] = ld_llc8(hp + kt * 32 + 4);
            qh[kt * 4 + 3] = ld_llc8(hp + kt * 32 + 6);
        }
        if (FUSED) {
#pragma unroll
            for (int kt = 0; kt < 2; ++kt) {
                qx[kt * 4 + 0] = ld_llc8(xp + kt * 32 + 0);
                qx[kt * 4 + 1] = ld_llc8(xp + kt * 32 + 2);
                qx[kt * 4 + 2] = ld_llc8(xp + kt * 32 + 4);
                qx[kt * 4 + 3] = ld_llc8(xp + kt * 32 + 6);
            }
        }

        f32x4 aH[4], aC[4];
#pragma unroll
        for (int g = 0; g < 4; ++g) { aH[g] = (f32x4){0,0,0,0}; aC[g] = (f32x4){0,0,0,0}; }

#pragma unroll
        for (int kt = 0; kt < 2; ++kt) {
            s16x8 ah, al;
            unpack_hl(qh[kt * 4 + 0], qh[kt * 4 + 1], qh[kt * 4 + 2], qh[kt * 4 + 3], ah, al);
#pragma unroll
            for (int g = 0; g < 4; ++g) {
                aH[g] = __builtin_amdgcn_mfma_f32_16x16x32_bf16(ah, whi[g][kt],  aH[g], 0, 0, 0);
                aC[g] = __builtin_amdgcn_mfma_f32_16x16x32_bf16(al, whi[g][kt],  aC[g], 0, 0, 0);
                aC[g] = __builtin_amdgcn_mfma_f32_16x16x32_bf16(ah, wlo_[g][kt], aC[g], 0, 0, 0);
            }
            if (FUSED) {
                s16x8 xh, xl;
                unpack_hl(qx[kt * 4 + 0], qx[kt * 4 + 1], qx[kt * 4 + 2], qx[kt * 4 + 3], xh, xl);
#pragma unroll
                for (int g = 0; g < 4; ++g) {
                    aH[g] = __builtin_amdgcn_mfma_f32_16x16x32_bf16(xh, vhi[g][kt],  aH[g], 0, 0, 0);
                    aC[g] = __builtin_amdgcn_mfma_f32_16x16x32_bf16(xl, vhi[g][kt],  aC[g], 0, 0, 0);
                    aC[g] = __builtin_amdgcn_mfma_f32_16x16x32_bf16(xh, vlo_[g][kt], aC[g], 0, 0, 0);
                }
            }
        }

        // cross-quarter combine via LDS, scalar conflict-free layout (barrier 1)
        const int idx = l4 * 16 + l15;
#pragma unroll
        for (int g = 0; g < 4; ++g) {
            f32x4 s = aH[g] + aC[g];
#pragma unroll
            for (int r = 0; r < 4; ++r)
                part[kq][js][g][r][idx] = s[r];
        }
        __syncthreads();

        float si  = part[0][js][0][kq][idx] + part[1][js][0][kq][idx]
                  + part[2][js][0][kq][idx] + part[3][js][0][kq][idx];
        float sf  = part[0][js][1][kq][idx] + part[1][js][1][kq][idx]
                  + part[2][js][1][kq][idx] + part[3][js][1][kq][idx];
        float sgg = part[0][js][2][kq][idx] + part[1][js][2][kq][idx]
                  + part[2][js][2][kq][idx] + part[3][js][2][kq][idx];
        float soo = part[0][js][3][kq][idx] + part[1][js][3][kq][idx]
                  + part[2][js][3][kq][idx] + part[3][js][3][kq][idx];

        if (!FUSED) { si += xv.x; sf += xv.y; sgg += xv.z; soo += xv.w; }
        else        { si += bsv.x; sf += bsv.y; sgg += bsv.z; soo += bsv.w; }

        float ig = sig_(si);
        float fg = sig_(sf);
        float gg = tanh_(sgg);
        float og = sig_(soo);
        cc = fmaf(fg, cc, ig * gg);
        hc = og * tanh_(cc);

        size_t pb = (size_t)((t + 1) & 1) * 16384;
        st_llc(&hxp[pb + (size_t)bown * 256 + jj], packhl(hc));
        if (a.ypkout != nullptr) {
            float hv = a.reluOut ? fmaxf(hc, 0.f) : hc;
            st_llc(&a.ypkout[((size_t)bown * TLEN + t) * 256 + jj], packhl(hv));
        }

        __syncthreads();   // barrier 2: drains publishes + LDS part WAR
        asm volatile("" ::: "memory");
        if (tid == 0) st_llc(&flg_own[wgm], (unsigned int)(t + 2));
    }

    if (a.h_save != nullptr) a.h_save[bown * 256 + jj] = hc;
    if (a.c_save != nullptr) a.c_save[bown * 256 + jj] = cc;
}

__global__ __launch_bounds__(512, 1) void rec_pipe(SArgs a0, SArgs a1,
                                                   unsigned int* hxp, unsigned int* flg)
{
    __shared__ float part[4][2][4][4][64];   // 32 KB, scalar conflict-free
    const int stage = blockIdx.x >> 5;
    const int sbid  = blockIdx.x & 31;
    const int gid   = sbid & 3;
    const int wgm   = sbid >> 2;
    unsigned int* myhxp = hxp + (size_t)stage * 32768;
    unsigned int* myflg = flg + stage * 32 + gid * 8;
    const unsigned int* srcflg = stage ? (flg + gid * 8) : nullptr;

    if (stage == 0) {
        if (a0.ypkin != nullptr) rec_stage<true >(a0, part, myhxp, myflg, srcflg, gid, wgm);
        else                     rec_stage<false>(a0, part, myhxp, myflg, srcflg, gid, wgm);
    } else {
        rec_stage<true>(a1, part, myhxp, myflg, srcflg, gid, wgm);
    }
}

// -------- head --------
__global__ __launch_bounds__(256) void head_kernel(const float* __restrict__ h3,
    const float* __restrict__ lin_w, const float* __restrict__ lin_b, float* __restrict__ out)
{
    int b = blockIdx.x;
    int tid = threadIdx.x;
    float v = h3[b * 256 + tid] * lin_w[tid];
#pragma unroll
    for (int o = 32; o > 0; o >>= 1) v += __shfl_down(v, o);
    __shared__ float red[4];
    int wid = tid >> 6, lane = tid & 63;
    if (lane == 0) red[wid] = v;
    __syncthreads();
    if (tid == 0) out[b] = red[0] + red[1] + red[2] + red[3] + lin_b[0];
}

extern "C" void kernel_launch(void* const* d_in, const int* in_sizes, int n_in,
                              void* d_out, int out_size, void* d_ws, size_t ws_size,
                              hipStream_t stream) {
    const float* x = (const float*)d_in[0];
    const float* wih[4] = { (const float*)d_in[1], (const float*)d_in[5], (const float*)d_in[9],  (const float*)d_in[13] };
    const float* whh[4] = { (const float*)d_in[2], (const float*)d_in[6], (const float*)d_in[10], (const float*)d_in[14] };
    const float* bih[4] = { (const float*)d_in[3], (const float*)d_in[7], (const float*)d_in[11], (const float*)d_in[15] };
    const float* bhh[4] = { (const float*)d_in[4], (const float*)d_in[8], (const float*)d_in[12], (const float*)d_in[16] };
    const float* lin_w = (const float*)d_in[17];
    const float* lin_b = (const float*)d_in[18];
    float* ws = (float*)d_ws;

    float* xg4 = ws + OFF_XG;
    unsigned int* y0pk = (unsigned int*)(ws + OFF_Y0PK);
    unsigned int* y1pk = (unsigned int*)(ws + OFF_Y1PK);
    unsigned int* y2pk = (unsigned int*)(ws + OFF_XG);
    float* wihT0 = ws + OFF_WIHT0;
    unsigned short* whhhiB = (unsigned short*)(ws + OFF_WHHHI);
    unsigned short* whhloB = (unsigned short*)(ws + OFF_WHHLO);
    unsigned short* wihhiB = (unsigned short*)(ws + OFF_WIHHI);
    unsigned short* wihloB = (unsigned short*)(ws + OFF_WIHLO);
    float* bsum = ws + OFF_BSUM;
    float* h0T = ws + OFF_STATE;
    float* c0T = h0T + 16384;
    float* h1T = c0T + 16384;
    float* c1T = h1T + 16384;
    float* h3T = c1T + 16384;
    unsigned int* hxp = (unsigned int*)(ws + OFF_HXP);
    unsigned int* flg = (unsigned int*)(ws + OFF_FLG);

    hipMemsetAsync(flg, 0, 128 * sizeof(int), stream);

    for (int l = 0; l < 4; ++l)
        prep_split<<<dim3(1024), 256, 0, stream>>>(whh[l], whhhiB + (size_t)l * 262144, whhloB + (size_t)l * 262144);
    for (int l = 1; l < 4; ++l)
        prep_split<<<dim3(1024), 256, 0, stream>>>(wih[l], wihhiB + (size_t)(l - 1) * 262144, wihloB + (size_t)(l - 1) * 262144);
    prep_wih<<<dim3(256), 256, 0, stream>>>(wih[0], wihT0, IDIM);
    for (int l = 0; l < 4; ++l)
        prep_bias<<<dim3(4), 256, 0, stream>>>(bih[l], bhh[l], bsum + l * 1024);

    proj_kernel<<<dim3(256, 8), 256, 0, stream>>>(x, IDIM, 1, wihT0, bsum + 0, xg4);

    SArgs a0 = { xg4, nullptr, nullptr, nullptr, nullptr,
                 y0pk, 0,
                 whhhiB + 0, whhloB + 0,
                 nullptr, nullptr, h0T, c0T };
    SArgs a1 = { nullptr, y0pk, wihhiB + 0, wihloB + 0, bsum + 1024,
                 y1pk, 1,
                 whhhiB + 262144, whhloB + 262144,
                 nullptr, nullptr, h1T, c1T };
    rec_pipe<<<dim3(64), 512, 0, stream>>>(a0, a1, hxp, flg);

    SArgs b0 = { nullptr, y1pk, wihhiB + 262144, wihloB + 262144, bsum + 2048,
                 y2pk, 0,
                 whhhiB + 2 * 262144, whhloB + 2 * 262144,
                 h0T, c0T, nullptr, nullptr };
    SArgs b1 = { nullptr, y2pk, wihhiB + 2 * 262144, wihloB + 2 * 262144, bsum + 3072,
                 nullptr, 0,
                 whhhiB + 3 * 262144, whhloB + 3 * 262144,
                 h1T, c1T, h3T, nullptr };
    rec_pipe<<<dim3(64), 512, 0, stream>>>(b0, b1, hxp, flg + 64);

    head_kernel<<<dim3(BATCH), 256, 0, stream>>>(h3T, lin_w, lin_b, (float*)d_out);
}